// Round 15
// baseline (1571.391 us; speedup 1.0000x reference)
//
#include <hip/hip_runtime.h>
#include <hip/hip_bf16.h>

#define D128 128
#define EPS 1e-5f

typedef unsigned short bfl;
typedef __bf16 bf16x8 __attribute__((ext_vector_type(8)));
typedef float f32x4 __attribute__((ext_vector_type(4)));

__device__ inline float bf2f(unsigned short u) { return __uint_as_float(((unsigned int)u) << 16); }
__device__ inline unsigned short f2bf(float f) {
    unsigned int x = __float_as_uint(f);
    return (unsigned short)((x + 0x7fffu + ((x >> 16) & 1u)) >> 16);  // RNE
}

// ---------------------------------------------------------------- CSR build
__global__ void dag_count_rank(const int* __restrict__ dst, int E,
                               int* __restrict__ deg, int* __restrict__ rank) {
    int i = blockIdx.x * blockDim.x + threadIdx.x;
    int stride = gridDim.x * blockDim.x;
    for (; i < E; i += stride) {
        int r = atomicAdd(&deg[dst[i]], 1);
        rank[i] = r;
    }
}

__global__ void dag_scan1(const int* __restrict__ deg, int N, int* __restrict__ out, int* __restrict__ partials) {
    __shared__ int sdata[256];
    int t = threadIdx.x;
    int base = blockIdx.x * 1024 + t * 4;
    int v[4]; int s = 0;
#pragma unroll
    for (int j = 0; j < 4; j++) { int idx = base + j; v[j] = (idx < N) ? deg[idx] : 0; s += v[j]; }
    sdata[t] = s; __syncthreads();
    for (int off = 1; off < 256; off <<= 1) {
        int x = (t >= off) ? sdata[t - off] : 0;
        __syncthreads();
        sdata[t] += x;
        __syncthreads();
    }
    int run = (t == 0) ? 0 : sdata[t - 1];
#pragma unroll
    for (int j = 0; j < 4; j++) { int idx = base + j; if (idx < N) out[idx] = run; run += v[j]; }
    if (t == 255) partials[blockIdx.x] = sdata[255];
}

__global__ void dag_scan2(int* __restrict__ partials, int P) {
    __shared__ int sdata[256];
    int t = threadIdx.x;
    int v = (t < P) ? partials[t] : 0;
    sdata[t] = v; __syncthreads();
    for (int off = 1; off < 256; off <<= 1) {
        int x = (t >= off) ? sdata[t - off] : 0;
        __syncthreads();
        sdata[t] += x;
        __syncthreads();
    }
    if (t < P) partials[t] = sdata[t] - v;  // exclusive
}

__global__ void dag_scan3(int* __restrict__ rowptr, const int* __restrict__ partials, int N, int E) {
    int i = blockIdx.x * blockDim.x + threadIdx.x;
    int stride = gridDim.x * blockDim.x;
    for (; i < N; i += stride) rowptr[i] += partials[i >> 10];
    if (blockIdx.x == 0 && threadIdx.x == 0) rowptr[N] = E;
}

__global__ void dag_place(const int* __restrict__ src, const int* __restrict__ dst,
                          const int* __restrict__ rank, const int* __restrict__ rowptr,
                          int E, int* __restrict__ csr_src) {
    int i = blockIdx.x * blockDim.x + threadIdx.x;
    int stride = gridDim.x * blockDim.x;
    for (; i < E; i += stride) {
        csr_src[rowptr[dst[i]] + rank[i]] = src[i];
    }
}

// ------------- weight convert: fp32 row-major -> bf16 transposed ----------
__global__ void dag_wconv(const float* __restrict__ node_W, const float* __restrict__ conv_W,
                          const float* __restrict__ k_weight, const float* __restrict__ attn_W1,
                          bfl* __restrict__ wt) {
    int i = blockIdx.x * blockDim.x + threadIdx.x;
    if (i >= 122880) return;
    float v;
    if (i < 8192) {                       // node_W [64,128] -> [128][64]
        int n = i >> 6, k = i & 63;
        v = node_W[k * 128 + n];
    } else if (i < 8192 + 49152) {        // conv_W [3][128][128] -> 3x[128][128]T
        int j = i - 8192; int k = j >> 14; int r = j & 16383;
        int n = r >> 7, kk = r & 127;
        v = conv_W[k * 16384 + kk * 128 + n];
    } else if (i < 8192 + 98304) {        // k_weight [384,128] -> 3x[128][128]T
        int j = i - 8192 - 49152; int k = j >> 14; int r = j & 16383;
        int n = r >> 7, kk = r & 127;
        v = k_weight[(k * 128 + kk) * 128 + n];
    } else {                              // attn_W1 [128,128] -> [128][128]T
        int j = i - 8192 - 98304;
        int n = j >> 7, kk = j & 127;
        v = attn_W1[kk * 128 + n];
    }
    wt[i] = f2bf(v);
}

// ---- finalize: sum 8 partial rows -> sc/sh; re-zero; optional kw fold ----
// part: [8][256] accumulated atomically by STATS gemms.
template<bool KWPREP>
__global__ void dag_finalize(float* __restrict__ part,
                             const float* __restrict__ g, const float* __restrict__ b,
                             float invN, float* __restrict__ slot,
                             const bfl* __restrict__ WtIn, bfl* __restrict__ Wt2,
                             float* __restrict__ bias2) {
    int t = threadIdx.x;  // 256
    float acc = 0.f;
#pragma unroll
    for (int i = 0; i < 8; i++) acc += part[i * 256 + t];
#pragma unroll
    for (int i = 0; i < 8; i++) part[i * 256 + t] = 0.f;   // ready for next use
    __shared__ float sums[256];
    __shared__ float scs[128], shs[128];
    sums[t] = acc;
    __syncthreads();
    if (t < 128) {
        float m = sums[t] * invN;
        float var = sums[128 + t] * invN - m * m;
        float scale = g[t] * rsqrtf(var + EPS);
        float shift = b[t] - m * scale;
        scs[t] = scale; shs[t] = shift;
        slot[t] = scale; slot[128 + t] = shift;
    }
    if constexpr (KWPREP) {
        __syncthreads();
        int row = t >> 1, half = t & 1;
        const bfl* wr = WtIn + row * 128 + half * 64;
        bfl* w2 = Wt2 + row * 128 + half * 64;
        float a = 0.f;
        for (int k = 0; k < 64; k += 8) {
            bf16x8 v = *(const bf16x8*)(wr + k);
            bfl o[8];
#pragma unroll
            for (int j = 0; j < 8; j++) {
                float f = (float)v[j];
                int kk = half * 64 + k + j;
                a += shs[kk] * f;
                o[j] = f2bf(scs[kk] * f);
            }
            *(bf16x8*)(w2 + k) = *(bf16x8*)o;
        }
        a += __shfl_xor(a, 1);
        if (half == 0) bias2[row] = a;
    }
}

// ----------------- register-weight MFMA GEMM, paired tiles ----------------
// STATS: per-block sums atomically added into part[blockIdx&7][256]
// (98-way per-address contention; part re-zeroed by dag_finalize).
template<int KSTEPS, int XMODE, bool BIAS, bool TANH, bool ACC, bool STATS>
__global__ __launch_bounds__(256) void gemm_rw(
        const void* __restrict__ Xv, const bfl* __restrict__ Wt,
        const float* __restrict__ bias, bfl* __restrict__ Y,
        int Nrows, float* __restrict__ partOut) {
    const int Kdim = KSTEPS * 32;
    int t = threadIdx.x;
    int lane = t & 63;
    int wave = t >> 6;
    int cg = wave & 1, rg = wave >> 1;
    int l15 = lane & 15, lg = lane >> 4;

    bf16x8 af[4][KSTEPS];
#pragma unroll
    for (int nf = 0; nf < 4; nf++)
#pragma unroll
        for (int ks = 0; ks < KSTEPS; ks++)
            af[nf][ks] = *(const bf16x8*)(Wt + (size_t)(cg * 64 + nf * 16 + l15) * Kdim + ks * 32 + lg * 8);

    float bia[4][4];
    if (BIAS) {
#pragma unroll
        for (int nf = 0; nf < 4; nf++) {
            float4 bb = *(const float4*)(bias + cg * 64 + nf * 16 + lg * 4);
            bia[nf][0] = bb.x; bia[nf][1] = bb.y; bia[nf][2] = bb.z; bia[nf][3] = bb.w;
        }
    }

    float s_c[4][4], q_c[4][4];
    if constexpr (STATS) {
#pragma unroll
        for (int nf = 0; nf < 4; nf++)
#pragma unroll
            for (int j = 0; j < 4; j++) { s_c[nf][j] = 0.f; q_c[nf][j] = 0.f; }
    }

    const int RT = (Nrows + 15) >> 4;
    const int step = gridDim.x * 2;

    auto load_bf = [&](int rt, bf16x8* bfo) {
        int r = rt * 16 + l15;
        bool valid = (rt < RT) && (r < Nrows);
#pragma unroll
        for (int ks = 0; ks < KSTEPS; ks++) {
            if (valid) {
                if (XMODE == 0) {
                    bfo[ks] = *(const bf16x8*)((const bfl*)Xv + (size_t)r * Kdim + ks * 32 + lg * 8);
                } else {
                    const float* xp = (const float*)Xv + (size_t)r * Kdim + ks * 32 + lg * 8;
                    float4 a4 = *(const float4*)xp;
                    float4 b4 = *(const float4*)(xp + 4);
                    bf16x8 bb;
                    bb[0] = (__bf16)a4.x; bb[1] = (__bf16)a4.y; bb[2] = (__bf16)a4.z; bb[3] = (__bf16)a4.w;
                    bb[4] = (__bf16)b4.x; bb[5] = (__bf16)b4.y; bb[6] = (__bf16)b4.z; bb[7] = (__bf16)b4.w;
                    bfo[ks] = bb;
                }
            } else {
                bf16x8 bb;
#pragma unroll
                for (int j = 0; j < 8; j++) bb[j] = (__bf16)0.f;
                bfo[ks] = bb;
            }
        }
    };

    auto compute_store = [&](int rt, const bf16x8* bfc) {
        int r = rt * 16 + l15;
        bool valid = (rt < RT) && (r < Nrows);
        f32x4 acc[4];
#pragma unroll
        for (int nf = 0; nf < 4; nf++) acc[nf] = (f32x4)0.f;
#pragma unroll
        for (int ks = 0; ks < KSTEPS; ks++)
#pragma unroll
            for (int nf = 0; nf < 4; nf++)
                acc[nf] = __builtin_amdgcn_mfma_f32_16x16x32_bf16(af[nf][ks], bfc[ks], acc[nf], 0, 0, 0);
#pragma unroll
        for (int nf = 0; nf < 4; nf++) {
            int c0 = cg * 64 + nf * 16 + lg * 4;
            f32x4 v = acc[nf];
            if (BIAS) {
#pragma unroll
                for (int j = 0; j < 4; j++) v[j] += bia[nf][j];
            }
            if (TANH) {
#pragma unroll
                for (int j = 0; j < 4; j++) v[j] = tanhf(v[j]);
            }
            if (valid) {
                bfl* yp = Y + (size_t)r * D128 + c0;
                if (ACC) {
                    ushort4 old = *(const ushort4*)yp;
                    v[0] += bf2f(old.x); v[1] += bf2f(old.y); v[2] += bf2f(old.z); v[3] += bf2f(old.w);
                }
                ushort4 o;
                o.x = f2bf(v[0]); o.y = f2bf(v[1]); o.z = f2bf(v[2]); o.w = f2bf(v[3]);
                *(ushort4*)yp = o;
            }
            if constexpr (STATS) {
#pragma unroll
                for (int j = 0; j < 4; j++) {
                    float f = valid ? v[j] : 0.f;
                    s_c[nf][j] += f;
                    q_c[nf][j] += f * f;
                }
            }
        }
    };

    for (int rt = blockIdx.x * 2 + rg; rt < RT; rt += 2 * step) {
        bf16x8 bfA[KSTEPS], bfB[KSTEPS];
        load_bf(rt, bfA);
        load_bf(rt + step, bfB);
        compute_store(rt, bfA);
        compute_store(rt + step, bfB);
    }

    if constexpr (STATS) {
#pragma unroll
        for (int nf = 0; nf < 4; nf++)
#pragma unroll
            for (int j = 0; j < 4; j++) {
                float s = s_c[nf][j], q = q_c[nf][j];
                s += __shfl_xor(s, 1); s += __shfl_xor(s, 2); s += __shfl_xor(s, 4); s += __shfl_xor(s, 8);
                q += __shfl_xor(q, 1); q += __shfl_xor(q, 2); q += __shfl_xor(q, 4); q += __shfl_xor(q, 8);
                s_c[nf][j] = s; q_c[nf][j] = q;
            }
        __shared__ float red[2][2][64];   // [cg][stat][col]
        ((float*)red)[t] = 0.f;
        __syncthreads();
        if (l15 == 0) {
#pragma unroll
            for (int nf = 0; nf < 4; nf++)
#pragma unroll
                for (int j = 0; j < 4; j++) {
                    int c = nf * 16 + lg * 4 + j;
                    atomicAdd(&red[cg][0][c], s_c[nf][j]);   // LDS atomics (block-local)
                    atomicAdd(&red[cg][1][c], q_c[nf][j]);
                }
        }
        __syncthreads();
        int cgi = t >> 7, stat = (t >> 6) & 1, c = t & 63;
        atomicAdd(&partOut[(size_t)(blockIdx.x & 7) * 256 + stat * 128 + cgi * 64 + c],
                  red[cgi][stat][c]);
    }
}

// --------- spmm body (shared by standalone + fused kernels) ---------------
__device__ inline void spmm_body(int n, int lane,
                                 const bfl* __restrict__ x, const bfl* __restrict__ bi,
                                 const int* __restrict__ rowptr, const int* __restrict__ csr_src,
                                 bfl* __restrict__ out, int N, const float* __restrict__ scsh) {
    if (n >= N) return;
    int c0 = lane * 2;
    float sc0 = 1.f, sc1 = 1.f, sh0 = 0.f, sh1 = 0.f;
    if (scsh) {
        sc0 = scsh[c0];     sh0 = scsh[128 + c0];
        sc1 = scsh[c0 + 1]; sh1 = scsh[128 + c0 + 1];
    }
    int p0 = rowptr[n], p1 = rowptr[n + 1];
    const bfl* xb = x + c0;
    float ax0 = 0.f, ax1 = 0.f, ax2 = 0.f, ax3 = 0.f;
    float ay0 = 0.f, ay1 = 0.f, ay2 = 0.f, ay3 = 0.f;
    int p = p0;
    for (; p + 4 <= p1; p += 4) {
        int s0 = csr_src[p], s1 = csr_src[p + 1], s2 = csr_src[p + 2], s3 = csr_src[p + 3];
        unsigned int u0 = *(const unsigned int*)(xb + (size_t)s0 * D128);
        unsigned int u1 = *(const unsigned int*)(xb + (size_t)s1 * D128);
        unsigned int u2 = *(const unsigned int*)(xb + (size_t)s2 * D128);
        unsigned int u3 = *(const unsigned int*)(xb + (size_t)s3 * D128);
        ax0 += __uint_as_float(u0 << 16); ay0 += __uint_as_float(u0 & 0xffff0000u);
        ax1 += __uint_as_float(u1 << 16); ay1 += __uint_as_float(u1 & 0xffff0000u);
        ax2 += __uint_as_float(u2 << 16); ay2 += __uint_as_float(u2 & 0xffff0000u);
        ax3 += __uint_as_float(u3 << 16); ay3 += __uint_as_float(u3 & 0xffff0000u);
    }
    for (; p < p1; p++) {
        int s0 = csr_src[p];
        unsigned int u0 = *(const unsigned int*)(xb + (size_t)s0 * D128);
        ax0 += __uint_as_float(u0 << 16); ay0 += __uint_as_float(u0 & 0xffff0000u);
    }
    float vx = (ax0 + ax1) + (ax2 + ax3);
    float vy = (ay0 + ay1) + (ay2 + ay3);
    float cnt = (float)(p1 - p0);
    unsigned int ub = *(const unsigned int*)(bi + (size_t)n * D128 + c0);
    vx = sc0 * vx + cnt * sh0 + __uint_as_float(ub << 16);
    vy = sc1 * vy + cnt * sh1 + __uint_as_float(ub & 0xffff0000u);
    unsigned int uo = (unsigned int)f2bf(vx) | ((unsigned int)f2bf(vy) << 16);
    *(unsigned int*)(out + (size_t)n * D128 + c0) = uo;
}

__global__ __launch_bounds__(256) void dag_spmm(
        const bfl* __restrict__ x, const bfl* __restrict__ bi,
        const int* __restrict__ rowptr, const int* __restrict__ csr_src,
        bfl* __restrict__ out, int N, const float* __restrict__ scsh) {
    spmm_body(blockIdx.x * 4 + (threadIdx.x >> 6), threadIdx.x & 63,
              x, bi, rowptr, csr_src, out, N, scsh);
}

// --------- FUSED: kw gemm (blocks < gB) ∥ spmm (blocks >= gB) -------------
// Both only READ P4; gemm writes P2, spmm writes P3 — independent, so they
// co-schedule without barriers (fills CUs: latency-bound gather + streaming
// MFMA).  ACC selects whether the gemm accumulates into Y.
template<bool ACC>
__global__ __launch_bounds__(256) void dag_kw_spmm(
        const bfl* __restrict__ X, const bfl* __restrict__ Wt2,
        const float* __restrict__ bias2, bfl* __restrict__ Y, int Nrows, int gB,
        const bfl* __restrict__ sbi, const int* __restrict__ rowptr,
        const int* __restrict__ csr_src, bfl* __restrict__ sout,
        const float* __restrict__ scsh) {
    int t = threadIdx.x;
    int lane = t & 63;
    int wave = t >> 6;
    if ((int)blockIdx.x >= gB) {
        // ---------------- spmm part: gather X rows -> sout
        spmm_body((blockIdx.x - gB) * 4 + wave, lane,
                  X, sbi, rowptr, csr_src, sout, Nrows, scsh);
        return;
    }
    // ---------------- gemm part: Y (+)= X @ Wt2 + bias2
    int cg = wave & 1, rg = wave >> 1;
    int l15 = lane & 15, lg = lane >> 4;
    bf16x8 af[4][4];
#pragma unroll
    for (int nf = 0; nf < 4; nf++)
#pragma unroll
        for (int ks = 0; ks < 4; ks++)
            af[nf][ks] = *(const bf16x8*)(Wt2 + (size_t)(cg * 64 + nf * 16 + l15) * D128 + ks * 32 + lg * 8);
    float bia[4][4];
#pragma unroll
    for (int nf = 0; nf < 4; nf++) {
        float4 bb = *(const float4*)(bias2 + cg * 64 + nf * 16 + lg * 4);
        bia[nf][0] = bb.x; bia[nf][1] = bb.y; bia[nf][2] = bb.z; bia[nf][3] = bb.w;
    }
    const int RT = (Nrows + 15) >> 4;
    const int step = gB * 2;
    auto load_bf = [&](int rt, bf16x8* bfo) {
        int r = rt * 16 + l15;
        bool valid = (rt < RT) && (r < Nrows);
#pragma unroll
        for (int ks = 0; ks < 4; ks++) {
            if (valid) bfo[ks] = *(const bf16x8*)(X + (size_t)r * D128 + ks * 32 + lg * 8);
            else {
                bf16x8 bb;
#pragma unroll
                for (int j = 0; j < 8; j++) bb[j] = (__bf16)0.f;
                bfo[ks] = bb;
            }
        }
    };
    auto compute_store = [&](int rt, const bf16x8* bfc) {
        int r = rt * 16 + l15;
        bool valid = (rt < RT) && (r < Nrows);
        f32x4 acc[4];
#pragma unroll
        for (int nf = 0; nf < 4; nf++) acc[nf] = (f32x4)0.f;
#pragma unroll
        for (int ks = 0; ks < 4; ks++)
#pragma unroll
            for (int nf = 0; nf < 4; nf++)
                acc[nf] = __builtin_amdgcn_mfma_f32_16x16x32_bf16(af[nf][ks], bfc[ks], acc[nf], 0, 0, 0);
#pragma unroll
        for (int nf = 0; nf < 4; nf++) {
            int c0 = cg * 64 + nf * 16 + lg * 4;
            f32x4 v = acc[nf];
#pragma unroll
            for (int j = 0; j < 4; j++) v[j] += bia[nf][j];
            if (valid) {
                bfl* yp = Y + (size_t)r * D128 + c0;
                if (ACC) {
                    ushort4 old = *(const ushort4*)yp;
                    v[0] += bf2f(old.x); v[1] += bf2f(old.y); v[2] += bf2f(old.z); v[3] += bf2f(old.w);
                }
                ushort4 o;
                o.x = f2bf(v[0]); o.y = f2bf(v[1]); o.z = f2bf(v[2]); o.w = f2bf(v[3]);
                *(ushort4*)yp = o;
            }
        }
    };
    for (int rt = blockIdx.x * 2 + rg; rt < RT; rt += 2 * step) {
        bf16x8 bfA[4], bfB[4];
        load_bf(rt, bfA);
        load_bf(rt + step, bfB);
        compute_store(rt, bfA);
        compute_store(rt + step, bfB);
    }
}

// ----------------- column stats fp32, small C (a2 [N,5]) ------------------
__global__ void dag_colstat_f32(const float* __restrict__ Y, int Nrows, int C, float* __restrict__ sums) {
    __shared__ float ls[8], lss[8];
    int t = threadIdx.x;
    int nlanes = blockDim.x / C;
    int col = t % C, lane = t / C;
    float s = 0.f, ss = 0.f;
    if (lane < nlanes) {
        for (int r = blockIdx.x * nlanes + lane; r < Nrows; r += gridDim.x * nlanes) {
            float v = Y[(size_t)r * C + col];
            s += v; ss += v * v;
        }
    }
    if (t < C) { ls[t] = 0.f; lss[t] = 0.f; }
    __syncthreads();
    if (lane < nlanes) { atomicAdd(&ls[col], s); atomicAdd(&lss[col], ss); }
    __syncthreads();
    if (t < C) { atomicAdd(&sums[t], ls[t]); atomicAdd(&sums[C + t], lss[t]); }
}

// --------- BN apply using finalized sc/sh + optional relu / bi out --------
template<bool RELU, bool ADDOUT>
__global__ void dag_bn_apply(bfl* __restrict__ Y, const float* __restrict__ scsh,
                             size_t n8,
                             const bfl* __restrict__ addin, bfl* __restrict__ out2) {
    __shared__ float sc[128], sh[128];
    int t = threadIdx.x;
    if (t < 128) {
        sc[t] = scsh[t];
        sh[t] = scsh[128 + t];
    }
    __syncthreads();
    for (size_t i = (size_t)blockIdx.x * blockDim.x + t; i < n8; i += (size_t)gridDim.x * blockDim.x) {
        int c0 = (int)((i * 8) & 127);
        bf16x8 v = *(bf16x8*)(Y + i * 8);
        bfl o[8], o2[8];
#pragma unroll
        for (int j = 0; j < 8; j++) {
            float f = (float)v[j] * sc[c0 + j] + sh[c0 + j];
            if (RELU) f = fmaxf(f, 0.f);
            o[j] = f2bf(f);
            if (ADDOUT) o2[j] = f2bf(f + bf2f(addin[i * 8 + j]));
        }
        *(bf16x8*)(Y + i * 8) = *(bf16x8*)o;
        if (ADDOUT) *(bf16x8*)(out2 + i * 8) = *(bf16x8*)o2;
    }
}

// --------------- small GEMM: Y[N,5] = (sc/sh-corrected X) @ W + b ---------
__global__ void dag_gemm5(const bfl* __restrict__ X, const float* __restrict__ W,
                          const float* __restrict__ bias, float* __restrict__ Y, int Nrows,
                          const float* __restrict__ scsh) {
    __shared__ float Xs[32][132];
    __shared__ float Ws[640];
    __shared__ float sc[128], sh[128];
    int t = threadIdx.x;
    if (t < 128) {
        sc[t] = scsh[t];
        sh[t] = scsh[128 + t];
    }
    for (int i = t; i < 640; i += 256) Ws[i] = W[i];
    __syncthreads();
    int row0 = blockIdx.x * 32;
#pragma unroll
    for (int i = 0; i < 2; i++) {
        int off = (i * 256 + t) * 8;
        int r = off >> 7, c = off & 127;
        int gr = row0 + r;
        if (gr < Nrows) {
            bf16x8 v = *(const bf16x8*)(X + (size_t)gr * D128 + c);
#pragma unroll
            for (int j = 0; j < 8; j++) Xs[r][c + j] = (float)v[j] * sc[c + j] + sh[c + j];
        } else {
#pragma unroll
            for (int j = 0; j < 8; j++) Xs[r][c + j] = 0.f;
        }
    }
    __syncthreads();
    if (t < 160) {
        int r = t / 5, h = t % 5;
        int gr = row0 + r;
        if (gr < Nrows) {
            float s = bias[h];
            for (int k = 0; k < 128; k++) s = fmaf(Xs[r][k], Ws[k * 5 + h], s);
            Y[(size_t)gr * 5 + h] = s;
        }
    }
}

// --------------- alpha: in-place bnb + softmax over 5 heads ---------------
__global__ void dag_alpha(float* __restrict__ a2, int N,
                          const float* __restrict__ sums, const float* __restrict__ g,
                          const float* __restrict__ b, float invN) {
    float scb[5], shb[5];
#pragma unroll
    for (int h = 0; h < 5; h++) {
        float s = sums[h], ss = sums[5 + h];
        float m = s * invN;
        float var = ss * invN - m * m;
        float scale = g[h] * rsqrtf(var + EPS);
        scb[h] = scale; shb[h] = b[h] - m * scale;
    }
    int n = blockIdx.x * blockDim.x + threadIdx.x;
    if (n >= N) return;
    float av[5];
    float mx = -1e30f;
#pragma unroll
    for (int h = 0; h < 5; h++) {
        av[h] = a2[(size_t)n * 5 + h] * scb[h] + shb[h];
        mx = fmaxf(mx, av[h]);
    }
    float s = 0.f;
#pragma unroll
    for (int h = 0; h < 5; h++) { av[h] = expf(av[h] - mx); s += av[h]; }
    float inv = 1.f / s;
#pragma unroll
    for (int h = 0; h < 5; h++) a2[(size_t)n * 5 + h] = av[h] * inv;
}

// --------------- attention pooling (alpha precomputed) --------------------
__global__ void dag_pool(const float* __restrict__ alpha, const bfl* __restrict__ emb,
                         const int* __restrict__ seg, int N, int G, float* __restrict__ out) {
    int gg = blockIdx.x;
    int d = threadIdx.x;  // 0..127
    int lo = 0, hi = N;
    while (lo < hi) { int m = (lo + hi) >> 1; if (seg[m] < gg) lo = m + 1; else hi = m; }
    int start = lo;
    lo = start; hi = N;
    while (lo < hi) { int m = (lo + hi) >> 1; if (seg[m] < gg + 1) lo = m + 1; else hi = m; }
    int end = lo;
    float acc[5] = {0.f, 0.f, 0.f, 0.f, 0.f};
    for (int n = start; n < end; n++) {
        float e = bf2f(emb[(size_t)n * D128 + d]);
#pragma unroll
        for (int h = 0; h < 5; h++) acc[h] = fmaf(alpha[(size_t)n * 5 + h], e, acc[h]);
    }
#pragma unroll
    for (int h = 0; h < 5; h++) out[(size_t)gg * 640 + h * D128 + d] = fmaxf(acc[h], 0.f);
}

// --------------- L1 regularizer (multi-block) -----------------------------
__global__ void dag_reg(const float* w0, int n0, const float* w1, int n1, const float* w2, int n2,
                        const float* w3, int n3, const float* w4, int n4, float* out, float invG) {
    __shared__ float sd[256];
    int t = threadIdx.x;
    int gt = blockIdx.x * blockDim.x + t;
    int stride = gridDim.x * blockDim.x;
    float s = 0.f;
    const float* ws[5] = {w0, w1, w2, w3, w4};
    int ns[5] = {n0, n1, n2, n3, n4};
    for (int a = 0; a < 5; a++) {
        const float* w = ws[a]; int n = ns[a];
        for (int i = gt; i < n; i += stride) s += fabsf(w[i]);
    }
    sd[t] = s; __syncthreads();
    for (int off = 128; off > 0; off >>= 1) { if (t < off) sd[t] += sd[t + off]; __syncthreads(); }
    if (t == 0) atomicAdd(out, sd[0] * invG);
}

// ================================================================ host side
extern "C" void kernel_launch(void* const* d_in, const int* in_sizes, int n_in,
                              void* d_out, int out_size, void* d_ws, size_t ws_size,
                              hipStream_t stream) {
    const float* node_feat = (const float*)d_in[0];
    const int*   src       = (const int*)d_in[1];
    const int*   dst       = (const int*)d_in[2];
    const int*   seg       = (const int*)d_in[3];
    const float* node_W    = (const float*)d_in[4];
    const float* node_b    = (const float*)d_in[5];
    const float* bn1_g     = (const float*)d_in[6];
    const float* bn1_b     = (const float*)d_in[7];
    const float* conv_W    = (const float*)d_in[8];
    const float* conv_b    = (const float*)d_in[9];
    const float* bn2_g     = (const float*)d_in[10];
    const float* bn2_b     = (const float*)d_in[11];
    const float* k_weight  = (const float*)d_in[12];
    const float* bn3_g     = (const float*)d_in[13];
    const float* bn3_b     = (const float*)d_in[14];
    const float* attn_W1   = (const float*)d_in[15];
    const float* attn_b1   = (const float*)d_in[16];
    const float* bna_g     = (const float*)d_in[17];
    const float* bna_b     = (const float*)d_in[18];
    const float* attn_W2   = (const float*)d_in[19];
    const float* attn_b2   = (const float*)d_in[20];
    const float* bnb_g     = (const float*)d_in[21];
    const float* bnb_b     = (const float*)d_in[22];

    const int N = in_sizes[3];
    const int E = in_sizes[1];
    const int G = (out_size - 1) / 640;
    const int FIN = in_sizes[0] / N;
    const float invN = 1.f / (float)N;

    // ---- workspace layout (all bf16 activations)
    auto align256 = [](size_t x) { return (x + 255) & ~(size_t)255; };
    size_t NB = (size_t)N * D128 * sizeof(bfl);   // 25.6 MB
    char* w = (char*)d_ws;
    bfl* P0 = (bfl*)(w + 0 * NB);   // inp (bn1 out)
    bfl* P1 = (bfl*)(w + 1 * NB);   // bi (block_input)
    bfl* P2 = (bfl*)(w + 2 * NB);   // cur / kgemm accumulator
    bfl* P3 = (bfl*)(w + 3 * NB);   // pooled / attn A
    bfl* P4 = (bfl*)(w + 4 * NB);   // O_k raw
    char* tail = w + 5 * NB;
    size_t off = 0;
    int gemmGrid = (N + 127) / 128;   // 782
    float* stats = (float*)(tail + off); off = align256(off + 15 * 256 * sizeof(float));
    float* part  = (float*)(tail + off); off = align256(off + 8 * 256 * sizeof(float));
    bfl*   wt    = (bfl*)(tail + off);   off = align256(off + 122880 * sizeof(bfl));
    bfl*   wt2   = (bfl*)(tail + off);   off = align256(off + 16384 * sizeof(bfl));
    float* bias2 = (float*)(tail + off); off = align256(off + 128 * sizeof(float));
    float* a2    = (float*)(tail + off); off = align256(off + (size_t)N * 5 * sizeof(float));
    int* deg     = (int*)(tail + off);   off = align256(off + (size_t)N * 4);
    int* rowptr  = (int*)(tail + off);   off = align256(off + (size_t)(N + 1) * 4);
    int* rank    = (int*)(tail + off);   off = align256(off + (size_t)E * 4);
    int* csr_src = (int*)(tail + off);   off = align256(off + (size_t)E * 4);
    int* partials= (int*)(tail + off);   off = align256(off + 512);

    bfl* wt_node = wt;
    bfl* wt_conv = wt + 8192;
    bfl* wt_kw   = wt + 8192 + 49152;
    bfl* wt_attn = wt + 8192 + 98304;
    auto slot = [&](int s) { return stats + (size_t)s * 256; };
    // slots 0..13 hold finalized {sc[128], sh[128]}; slot 14 = raw bnb sums

    int spmmGrid = (N + 3) / 4;
    int fusedGrid = gemmGrid + spmmGrid;

    // ---- zero part accumulator (8 rows), slot14 sums, reg output slot
    hipMemsetAsync(part, 0, 8 * 256 * sizeof(float), stream);
    hipMemsetAsync(slot(14), 0, 256 * sizeof(float), stream);
    hipMemsetAsync((float*)d_out + (size_t)G * 640, 0, 4, stream);

    // ---- CSR build (by dst): one atomic pass + scan + non-atomic place
    hipMemsetAsync(deg, 0, (size_t)N * 4, stream);
    dag_count_rank<<<1024, 256, 0, stream>>>(dst, E, deg, rank);
    int P = (N + 1023) / 1024;
    dag_scan1<<<P, 256, 0, stream>>>(deg, N, rowptr, partials);
    dag_scan2<<<1, 256, 0, stream>>>(partials, P);
    dag_scan3<<<256, 256, 0, stream>>>(rowptr, partials, N, E);
    dag_place<<<1024, 256, 0, stream>>>(src, dst, rank, rowptr, E, csr_src);

    // ---- weights -> bf16 transposed
    dag_wconv<<<480, 256, 0, stream>>>(node_W, conv_W, k_weight, attn_W1, wt);

    // ---- L1 reg (independent)
    dag_reg<<<64, 256, 0, stream>>>(node_W, FIN * D128, conv_W, 3 * D128 * D128,
                                    k_weight, 3 * D128 * D128, attn_W1, D128 * D128,
                                    attn_W2, D128 * 5, (float*)d_out + (size_t)G * 640, 1.0f / G);

    // ---- node embedding: P0 = relu(bn1(node_feat @ node_W + node_b))
    gemm_rw<2, 1, true, false, false, true><<<gemmGrid, 256, 0, stream>>>(
        node_feat, wt_node, node_b, P0, N, part);
    dag_finalize<false><<<1, 256, 0, stream>>>(part, bn1_g, bn1_b, invN,
                                               slot(0), nullptr, nullptr, nullptr);
    dag_bn_apply<true, false><<<2048, 256, 0, stream>>>(P0, slot(0), (size_t)N * D128 / 8,
                                                        nullptr, nullptr);

    // ---- 3 blocks
    for (int blk = 0; blk < 3; blk++) {
        const bfl* bip = (blk == 0) ? P0 : P1;
        for (int k = 0; k < 3; k++) {
            int s2i = 1 + blk * 3 + k;
            // spmm(k): only standalone for k=0 (k>=1 fused below with kw(k-1))
            if (k == 0)
                dag_spmm<<<spmmGrid, 256, 0, stream>>>(bip, bip, rowptr, csr_src, P3, N, nullptr);
            // conv(k): P3 -> P4 (raw; bn2 partials -> part)
            gemm_rw<4, 0, true, false, false, true><<<gemmGrid, 256, 0, stream>>>(
                P3, wt_conv + (size_t)k * 16384, conv_b + k * D128, P4, N, part);
            // finalize bn2 -> slot(s2i) AND build wt2/bias2
            dag_finalize<true><<<1, 256, 0, stream>>>(part,
                                                      bn2_g + k * D128, bn2_b + k * D128, invN,
                                                      slot(s2i), wt_kw + (size_t)k * 16384, wt2, bias2);
            // kw(k): P2 (+)= P4 @ wt2 + bias2
            //   k<2: fused with spmm(k+1) (gather P4 -> P3 w/ slot(s2i)) — both read-only on P4
            //   k==2: standalone, with bn3 partials
            if (k == 0)
                dag_kw_spmm<false><<<fusedGrid, 256, 0, stream>>>(
                    P4, wt2, bias2, P2, N, gemmGrid,
                    bip, rowptr, csr_src, P3, slot(s2i));
            else if (k == 1)
                dag_kw_spmm<true><<<fusedGrid, 256, 0, stream>>>(
                    P4, wt2, bias2, P2, N, gemmGrid,
                    bip, rowptr, csr_src, P3, slot(s2i));
            else
                gemm_rw<4, 0, true, false, true, true><<<gemmGrid, 256, 0, stream>>>(
                    P4, wt2, bias2, P2, N, part);
        }
        dag_finalize<false><<<1, 256, 0, stream>>>(part, bn3_g, bn3_b, invN,
                                                   slot(10 + blk), nullptr, nullptr, nullptr);
        // P2 = relu(bn3(P2)); for blk<2 also P1 = P2 + P0
        if (blk < 2)
            dag_bn_apply<true, true><<<2048, 256, 0, stream>>>(P2, slot(10 + blk),
                                                               (size_t)N * D128 / 8, P0, P1);
        else
            dag_bn_apply<true, false><<<2048, 256, 0, stream>>>(P2, slot(10 + blk),
                                                                (size_t)N * D128 / 8, nullptr, nullptr);
    }

    // ---- attention pooling (bna partials from tanh-gemm)
    gemm_rw<4, 0, true, true, false, true><<<gemmGrid, 256, 0, stream>>>(
        P2, wt_attn, attn_b1, P3, N, part);
    dag_finalize<false><<<1, 256, 0, stream>>>(part, bna_g, bna_b, invN,
                                               slot(13), nullptr, nullptr, nullptr);
    dag_gemm5<<<(N + 31) / 32, 256, 0, stream>>>(P3, attn_W2, attn_b2, a2, N, slot(13));
    dag_colstat_f32<<<256, 255, 0, stream>>>(a2, N, 5, slot(14));
    dag_alpha<<<(N + 255) / 256, 256, 0, stream>>>(a2, N, slot(14), bnb_g, bnb_b, invN);
    dag_pool<<<G, 128, 0, stream>>>(a2, P2, seg, N, G, (float*)d_out);
}

// Round 16
// 1252.328 us; speedup vs baseline: 1.2548x; 1.2548x over previous
//
#include <hip/hip_runtime.h>
#include <hip/hip_bf16.h>

#define D128 128
#define EPS 1e-5f

typedef unsigned short bfl;
typedef __bf16 bf16x8 __attribute__((ext_vector_type(8)));
typedef float f32x4 __attribute__((ext_vector_type(4)));

__device__ inline float bf2f(unsigned short u) { return __uint_as_float(((unsigned int)u) << 16); }
__device__ inline unsigned short f2bf(float f) {
    unsigned int x = __float_as_uint(f);
    return (unsigned short)((x + 0x7fffu + ((x >> 16) & 1u)) >> 16);  // RNE
}

// ---------------------------------------------------------------- CSR build
__global__ void dag_count_rank(const int* __restrict__ dst, int E,
                               int* __restrict__ deg, int* __restrict__ rank) {
    int i = blockIdx.x * blockDim.x + threadIdx.x;
    int stride = gridDim.x * blockDim.x;
    for (; i < E; i += stride) {
        int r = atomicAdd(&deg[dst[i]], 1);
        rank[i] = r;
    }
}

__global__ void dag_scan1(const int* __restrict__ deg, int N, int* __restrict__ out, int* __restrict__ partials) {
    __shared__ int sdata[256];
    int t = threadIdx.x;
    int base = blockIdx.x * 1024 + t * 4;
    int v[4]; int s = 0;
#pragma unroll
    for (int j = 0; j < 4; j++) { int idx = base + j; v[j] = (idx < N) ? deg[idx] : 0; s += v[j]; }
    sdata[t] = s; __syncthreads();
    for (int off = 1; off < 256; off <<= 1) {
        int x = (t >= off) ? sdata[t - off] : 0;
        __syncthreads();
        sdata[t] += x;
        __syncthreads();
    }
    int run = (t == 0) ? 0 : sdata[t - 1];
#pragma unroll
    for (int j = 0; j < 4; j++) { int idx = base + j; if (idx < N) out[idx] = run; run += v[j]; }
    if (t == 255) partials[blockIdx.x] = sdata[255];
}

__global__ void dag_scan2(int* __restrict__ partials, int P) {
    __shared__ int sdata[256];
    int t = threadIdx.x;
    int v = (t < P) ? partials[t] : 0;
    sdata[t] = v; __syncthreads();
    for (int off = 1; off < 256; off <<= 1) {
        int x = (t >= off) ? sdata[t - off] : 0;
        __syncthreads();
        sdata[t] += x;
        __syncthreads();
    }
    if (t < P) partials[t] = sdata[t] - v;  // exclusive
}

__global__ void dag_scan3(int* __restrict__ rowptr, const int* __restrict__ partials, int N, int E) {
    int i = blockIdx.x * blockDim.x + threadIdx.x;
    int stride = gridDim.x * blockDim.x;
    for (; i < N; i += stride) rowptr[i] += partials[i >> 10];
    if (blockIdx.x == 0 && threadIdx.x == 0) rowptr[N] = E;
}

__global__ void dag_place(const int* __restrict__ src, const int* __restrict__ dst,
                          const int* __restrict__ rank, const int* __restrict__ rowptr,
                          int E, int* __restrict__ csr_src) {
    int i = blockIdx.x * blockDim.x + threadIdx.x;
    int stride = gridDim.x * blockDim.x;
    for (; i < E; i += stride) {
        csr_src[rowptr[dst[i]] + rank[i]] = src[i];
    }
}

// ------------- weight convert: fp32 row-major -> bf16 transposed ----------
__global__ void dag_wconv(const float* __restrict__ node_W, const float* __restrict__ conv_W,
                          const float* __restrict__ k_weight, const float* __restrict__ attn_W1,
                          bfl* __restrict__ wt) {
    int i = blockIdx.x * blockDim.x + threadIdx.x;
    if (i >= 122880) return;
    float v;
    if (i < 8192) {                       // node_W [64,128] -> [128][64]
        int n = i >> 6, k = i & 63;
        v = node_W[k * 128 + n];
    } else if (i < 8192 + 49152) {        // conv_W [3][128][128] -> 3x[128][128]T
        int j = i - 8192; int k = j >> 14; int r = j & 16383;
        int n = r >> 7, kk = r & 127;
        v = conv_W[k * 16384 + kk * 128 + n];
    } else if (i < 8192 + 98304) {        // k_weight [384,128] -> 3x[128][128]T
        int j = i - 8192 - 49152; int k = j >> 14; int r = j & 16383;
        int n = r >> 7, kk = r & 127;
        v = k_weight[(k * 128 + kk) * 128 + n];
    } else {                              // attn_W1 [128,128] -> [128][128]T
        int j = i - 8192 - 98304;
        int n = j >> 7, kk = j & 127;
        v = attn_W1[kk * 128 + n];
    }
    wt[i] = f2bf(v);
}

// ---- finalize: sum 8 partial rows -> sc/sh; re-zero; optional kw fold ----
// part: [8][256] accumulated atomically by STATS gemms.
template<bool KWPREP>
__global__ void dag_finalize(float* __restrict__ part,
                             const float* __restrict__ g, const float* __restrict__ b,
                             float invN, float* __restrict__ slot,
                             const bfl* __restrict__ WtIn, bfl* __restrict__ Wt2,
                             float* __restrict__ bias2) {
    int t = threadIdx.x;  // 256
    float acc = 0.f;
#pragma unroll
    for (int i = 0; i < 8; i++) acc += part[i * 256 + t];
#pragma unroll
    for (int i = 0; i < 8; i++) part[i * 256 + t] = 0.f;   // ready for next use
    __shared__ float sums[256];
    __shared__ float scs[128], shs[128];
    sums[t] = acc;
    __syncthreads();
    if (t < 128) {
        float m = sums[t] * invN;
        float var = sums[128 + t] * invN - m * m;
        float scale = g[t] * rsqrtf(var + EPS);
        float shift = b[t] - m * scale;
        scs[t] = scale; shs[t] = shift;
        slot[t] = scale; slot[128 + t] = shift;
    }
    if constexpr (KWPREP) {
        __syncthreads();
        int row = t >> 1, half = t & 1;
        const bfl* wr = WtIn + row * 128 + half * 64;
        bfl* w2 = Wt2 + row * 128 + half * 64;
        float a = 0.f;
        for (int k = 0; k < 64; k += 8) {
            bf16x8 v = *(const bf16x8*)(wr + k);
            bfl o[8];
#pragma unroll
            for (int j = 0; j < 8; j++) {
                float f = (float)v[j];
                int kk = half * 64 + k + j;
                a += shs[kk] * f;
                o[j] = f2bf(scs[kk] * f);
            }
            *(bf16x8*)(w2 + k) = *(bf16x8*)o;
        }
        a += __shfl_xor(a, 1);
        if (half == 0) bias2[row] = a;
    }
}

// ----------------- register-weight MFMA GEMM, paired tiles ----------------
// STATS: per-block sums atomically added into part[blockIdx&7][256]
// (98-way per-address contention; part re-zeroed by dag_finalize).
template<int KSTEPS, int XMODE, bool BIAS, bool TANH, bool ACC, bool STATS>
__global__ __launch_bounds__(256) void gemm_rw(
        const void* __restrict__ Xv, const bfl* __restrict__ Wt,
        const float* __restrict__ bias, bfl* __restrict__ Y,
        int Nrows, float* __restrict__ partOut) {
    const int Kdim = KSTEPS * 32;
    int t = threadIdx.x;
    int lane = t & 63;
    int wave = t >> 6;
    int cg = wave & 1, rg = wave >> 1;
    int l15 = lane & 15, lg = lane >> 4;

    bf16x8 af[4][KSTEPS];
#pragma unroll
    for (int nf = 0; nf < 4; nf++)
#pragma unroll
        for (int ks = 0; ks < KSTEPS; ks++)
            af[nf][ks] = *(const bf16x8*)(Wt + (size_t)(cg * 64 + nf * 16 + l15) * Kdim + ks * 32 + lg * 8);

    float bia[4][4];
    if (BIAS) {
#pragma unroll
        for (int nf = 0; nf < 4; nf++) {
            float4 bb = *(const float4*)(bias + cg * 64 + nf * 16 + lg * 4);
            bia[nf][0] = bb.x; bia[nf][1] = bb.y; bia[nf][2] = bb.z; bia[nf][3] = bb.w;
        }
    }

    float s_c[4][4], q_c[4][4];
    if constexpr (STATS) {
#pragma unroll
        for (int nf = 0; nf < 4; nf++)
#pragma unroll
            for (int j = 0; j < 4; j++) { s_c[nf][j] = 0.f; q_c[nf][j] = 0.f; }
    }

    const int RT = (Nrows + 15) >> 4;
    const int step = gridDim.x * 2;

    auto load_bf = [&](int rt, bf16x8* bfo) {
        int r = rt * 16 + l15;
        bool valid = (rt < RT) && (r < Nrows);
#pragma unroll
        for (int ks = 0; ks < KSTEPS; ks++) {
            if (valid) {
                if (XMODE == 0) {
                    bfo[ks] = *(const bf16x8*)((const bfl*)Xv + (size_t)r * Kdim + ks * 32 + lg * 8);
                } else {
                    const float* xp = (const float*)Xv + (size_t)r * Kdim + ks * 32 + lg * 8;
                    float4 a4 = *(const float4*)xp;
                    float4 b4 = *(const float4*)(xp + 4);
                    bf16x8 bb;
                    bb[0] = (__bf16)a4.x; bb[1] = (__bf16)a4.y; bb[2] = (__bf16)a4.z; bb[3] = (__bf16)a4.w;
                    bb[4] = (__bf16)b4.x; bb[5] = (__bf16)b4.y; bb[6] = (__bf16)b4.z; bb[7] = (__bf16)b4.w;
                    bfo[ks] = bb;
                }
            } else {
                bf16x8 bb;
#pragma unroll
                for (int j = 0; j < 8; j++) bb[j] = (__bf16)0.f;
                bfo[ks] = bb;
            }
        }
    };

    auto compute_store = [&](int rt, const bf16x8* bfc) {
        int r = rt * 16 + l15;
        bool valid = (rt < RT) && (r < Nrows);
        f32x4 acc[4];
#pragma unroll
        for (int nf = 0; nf < 4; nf++) acc[nf] = (f32x4)0.f;
#pragma unroll
        for (int ks = 0; ks < KSTEPS; ks++)
#pragma unroll
            for (int nf = 0; nf < 4; nf++)
                acc[nf] = __builtin_amdgcn_mfma_f32_16x16x32_bf16(af[nf][ks], bfc[ks], acc[nf], 0, 0, 0);
#pragma unroll
        for (int nf = 0; nf < 4; nf++) {
            int c0 = cg * 64 + nf * 16 + lg * 4;
            f32x4 v = acc[nf];
            if (BIAS) {
#pragma unroll
                for (int j = 0; j < 4; j++) v[j] += bia[nf][j];
            }
            if (TANH) {
#pragma unroll
                for (int j = 0; j < 4; j++) v[j] = tanhf(v[j]);
            }
            if (valid) {
                bfl* yp = Y + (size_t)r * D128 + c0;
                if (ACC) {
                    ushort4 old = *(const ushort4*)yp;
                    v[0] += bf2f(old.x); v[1] += bf2f(old.y); v[2] += bf2f(old.z); v[3] += bf2f(old.w);
                }
                ushort4 o;
                o.x = f2bf(v[0]); o.y = f2bf(v[1]); o.z = f2bf(v[2]); o.w = f2bf(v[3]);
                *(ushort4*)yp = o;
            }
            if constexpr (STATS) {
#pragma unroll
                for (int j = 0; j < 4; j++) {
                    float f = valid ? v[j] : 0.f;
                    s_c[nf][j] += f;
                    q_c[nf][j] += f * f;
                }
            }
        }
    };

    for (int rt = blockIdx.x * 2 + rg; rt < RT; rt += 2 * step) {
        bf16x8 bfA[KSTEPS], bfB[KSTEPS];
        load_bf(rt, bfA);
        load_bf(rt + step, bfB);
        compute_store(rt, bfA);
        compute_store(rt + step, bfB);
    }

    if constexpr (STATS) {
#pragma unroll
        for (int nf = 0; nf < 4; nf++)
#pragma unroll
            for (int j = 0; j < 4; j++) {
                float s = s_c[nf][j], q = q_c[nf][j];
                s += __shfl_xor(s, 1); s += __shfl_xor(s, 2); s += __shfl_xor(s, 4); s += __shfl_xor(s, 8);
                q += __shfl_xor(q, 1); q += __shfl_xor(q, 2); q += __shfl_xor(q, 4); q += __shfl_xor(q, 8);
                s_c[nf][j] = s; q_c[nf][j] = q;
            }
        __shared__ float red[2][2][64];   // [cg][stat][col]
        ((float*)red)[t] = 0.f;
        __syncthreads();
        if (l15 == 0) {
#pragma unroll
            for (int nf = 0; nf < 4; nf++)
#pragma unroll
                for (int j = 0; j < 4; j++) {
                    int c = nf * 16 + lg * 4 + j;
                    atomicAdd(&red[cg][0][c], s_c[nf][j]);   // LDS atomics (block-local)
                    atomicAdd(&red[cg][1][c], q_c[nf][j]);
                }
        }
        __syncthreads();
        int cgi = t >> 7, stat = (t >> 6) & 1, c = t & 63;
        atomicAdd(&partOut[(size_t)(blockIdx.x & 7) * 256 + stat * 128 + cgi * 64 + c],
                  red[cgi][stat][c]);
    }
}

// --------- spmm, wave-per-node: out = sc*sum(x_raw) + cnt*sh + bi ---------
__global__ __launch_bounds__(256) void dag_spmm(
        const bfl* __restrict__ x, const bfl* __restrict__ bi,
        const int* __restrict__ rowptr, const int* __restrict__ csr_src,
        bfl* __restrict__ out, int N, const float* __restrict__ scsh) {
    int lane = threadIdx.x & 63;
    int n = blockIdx.x * 4 + (threadIdx.x >> 6);
    if (n >= N) return;
    int c0 = lane * 2;
    float sc0 = 1.f, sc1 = 1.f, sh0 = 0.f, sh1 = 0.f;
    if (scsh) {
        sc0 = scsh[c0];     sh0 = scsh[128 + c0];
        sc1 = scsh[c0 + 1]; sh1 = scsh[128 + c0 + 1];
    }
    int p0 = rowptr[n], p1 = rowptr[n + 1];
    const bfl* xb = x + c0;
    float ax0 = 0.f, ax1 = 0.f, ax2 = 0.f, ax3 = 0.f;
    float ay0 = 0.f, ay1 = 0.f, ay2 = 0.f, ay3 = 0.f;
    int p = p0;
    for (; p + 4 <= p1; p += 4) {
        int s0 = csr_src[p], s1 = csr_src[p + 1], s2 = csr_src[p + 2], s3 = csr_src[p + 3];
        unsigned int u0 = *(const unsigned int*)(xb + (size_t)s0 * D128);
        unsigned int u1 = *(const unsigned int*)(xb + (size_t)s1 * D128);
        unsigned int u2 = *(const unsigned int*)(xb + (size_t)s2 * D128);
        unsigned int u3 = *(const unsigned int*)(xb + (size_t)s3 * D128);
        ax0 += __uint_as_float(u0 << 16); ay0 += __uint_as_float(u0 & 0xffff0000u);
        ax1 += __uint_as_float(u1 << 16); ay1 += __uint_as_float(u1 & 0xffff0000u);
        ax2 += __uint_as_float(u2 << 16); ay2 += __uint_as_float(u2 & 0xffff0000u);
        ax3 += __uint_as_float(u3 << 16); ay3 += __uint_as_float(u3 & 0xffff0000u);
    }
    for (; p < p1; p++) {
        int s0 = csr_src[p];
        unsigned int u0 = *(const unsigned int*)(xb + (size_t)s0 * D128);
        ax0 += __uint_as_float(u0 << 16); ay0 += __uint_as_float(u0 & 0xffff0000u);
    }
    float vx = (ax0 + ax1) + (ax2 + ax3);
    float vy = (ay0 + ay1) + (ay2 + ay3);
    float cnt = (float)(p1 - p0);
    unsigned int ub = *(const unsigned int*)(bi + (size_t)n * D128 + c0);
    vx = sc0 * vx + cnt * sh0 + __uint_as_float(ub << 16);
    vy = sc1 * vy + cnt * sh1 + __uint_as_float(ub & 0xffff0000u);
    unsigned int uo = (unsigned int)f2bf(vx) | ((unsigned int)f2bf(vy) << 16);
    *(unsigned int*)(out + (size_t)n * D128 + c0) = uo;
}

// ----------------- column stats fp32, small C (a2 [N,5]) ------------------
__global__ void dag_colstat_f32(const float* __restrict__ Y, int Nrows, int C, float* __restrict__ sums) {
    __shared__ float ls[8], lss[8];
    int t = threadIdx.x;
    int nlanes = blockDim.x / C;
    int col = t % C, lane = t / C;
    float s = 0.f, ss = 0.f;
    if (lane < nlanes) {
        for (int r = blockIdx.x * nlanes + lane; r < Nrows; r += gridDim.x * nlanes) {
            float v = Y[(size_t)r * C + col];
            s += v; ss += v * v;
        }
    }
    if (t < C) { ls[t] = 0.f; lss[t] = 0.f; }
    __syncthreads();
    if (lane < nlanes) { atomicAdd(&ls[col], s); atomicAdd(&lss[col], ss); }
    __syncthreads();
    if (t < C) { atomicAdd(&sums[t], ls[t]); atomicAdd(&sums[C + t], lss[t]); }
}

// --------- BN apply using finalized sc/sh + optional relu / bi out --------
template<bool RELU, bool ADDOUT>
__global__ void dag_bn_apply(bfl* __restrict__ Y, const float* __restrict__ scsh,
                             size_t n8,
                             const bfl* __restrict__ addin, bfl* __restrict__ out2) {
    __shared__ float sc[128], sh[128];
    int t = threadIdx.x;
    if (t < 128) {
        sc[t] = scsh[t];
        sh[t] = scsh[128 + t];
    }
    __syncthreads();
    for (size_t i = (size_t)blockIdx.x * blockDim.x + t; i < n8; i += (size_t)gridDim.x * blockDim.x) {
        int c0 = (int)((i * 8) & 127);
        bf16x8 v = *(bf16x8*)(Y + i * 8);
        bfl o[8], o2[8];
#pragma unroll
        for (int j = 0; j < 8; j++) {
            float f = (float)v[j] * sc[c0 + j] + sh[c0 + j];
            if (RELU) f = fmaxf(f, 0.f);
            o[j] = f2bf(f);
            if (ADDOUT) o2[j] = f2bf(f + bf2f(addin[i * 8 + j]));
        }
        *(bf16x8*)(Y + i * 8) = *(bf16x8*)o;
        if (ADDOUT) *(bf16x8*)(out2 + i * 8) = *(bf16x8*)o2;
    }
}

// --------------- small GEMM: Y[N,5] = (sc/sh-corrected X) @ W + b ---------
__global__ void dag_gemm5(const bfl* __restrict__ X, const float* __restrict__ W,
                          const float* __restrict__ bias, float* __restrict__ Y, int Nrows,
                          const float* __restrict__ scsh) {
    __shared__ float Xs[32][132];
    __shared__ float Ws[640];
    __shared__ float sc[128], sh[128];
    int t = threadIdx.x;
    if (t < 128) {
        sc[t] = scsh[t];
        sh[t] = scsh[128 + t];
    }
    for (int i = t; i < 640; i += 256) Ws[i] = W[i];
    __syncthreads();
    int row0 = blockIdx.x * 32;
#pragma unroll
    for (int i = 0; i < 2; i++) {
        int off = (i * 256 + t) * 8;
        int r = off >> 7, c = off & 127;
        int gr = row0 + r;
        if (gr < Nrows) {
            bf16x8 v = *(const bf16x8*)(X + (size_t)gr * D128 + c);
#pragma unroll
            for (int j = 0; j < 8; j++) Xs[r][c + j] = (float)v[j] * sc[c + j] + sh[c + j];
        } else {
#pragma unroll
            for (int j = 0; j < 8; j++) Xs[r][c + j] = 0.f;
        }
    }
    __syncthreads();
    if (t < 160) {
        int r = t / 5, h = t % 5;
        int gr = row0 + r;
        if (gr < Nrows) {
            float s = bias[h];
            for (int k = 0; k < 128; k++) s = fmaf(Xs[r][k], Ws[k * 5 + h], s);
            Y[(size_t)gr * 5 + h] = s;
        }
    }
}

// --------------- alpha: in-place bnb + softmax over 5 heads ---------------
__global__ void dag_alpha(float* __restrict__ a2, int N,
                          const float* __restrict__ sums, const float* __restrict__ g,
                          const float* __restrict__ b, float invN) {
    float scb[5], shb[5];
#pragma unroll
    for (int h = 0; h < 5; h++) {
        float s = sums[h], ss = sums[5 + h];
        float m = s * invN;
        float var = ss * invN - m * m;
        float scale = g[h] * rsqrtf(var + EPS);
        scb[h] = scale; shb[h] = b[h] - m * scale;
    }
    int n = blockIdx.x * blockDim.x + threadIdx.x;
    if (n >= N) return;
    float av[5];
    float mx = -1e30f;
#pragma unroll
    for (int h = 0; h < 5; h++) {
        av[h] = a2[(size_t)n * 5 + h] * scb[h] + shb[h];
        mx = fmaxf(mx, av[h]);
    }
    float s = 0.f;
#pragma unroll
    for (int h = 0; h < 5; h++) { av[h] = expf(av[h] - mx); s += av[h]; }
    float inv = 1.f / s;
#pragma unroll
    for (int h = 0; h < 5; h++) a2[(size_t)n * 5 + h] = av[h] * inv;
}

// --------------- attention pooling (alpha precomputed) --------------------
__global__ void dag_pool(const float* __restrict__ alpha, const bfl* __restrict__ emb,
                         const int* __restrict__ seg, int N, int G, float* __restrict__ out) {
    int gg = blockIdx.x;
    int d = threadIdx.x;  // 0..127
    int lo = 0, hi = N;
    while (lo < hi) { int m = (lo + hi) >> 1; if (seg[m] < gg) lo = m + 1; else hi = m; }
    int start = lo;
    lo = start; hi = N;
    while (lo < hi) { int m = (lo + hi) >> 1; if (seg[m] < gg + 1) lo = m + 1; else hi = m; }
    int end = lo;
    float acc[5] = {0.f, 0.f, 0.f, 0.f, 0.f};
    for (int n = start; n < end; n++) {
        float e = bf2f(emb[(size_t)n * D128 + d]);
#pragma unroll
        for (int h = 0; h < 5; h++) acc[h] = fmaf(alpha[(size_t)n * 5 + h], e, acc[h]);
    }
#pragma unroll
    for (int h = 0; h < 5; h++) out[(size_t)gg * 640 + h * D128 + d] = fmaxf(acc[h], 0.f);
}

// --------------- L1 regularizer (multi-block) -----------------------------
__global__ void dag_reg(const float* w0, int n0, const float* w1, int n1, const float* w2, int n2,
                        const float* w3, int n3, const float* w4, int n4, float* out, float invG) {
    __shared__ float sd[256];
    int t = threadIdx.x;
    int gt = blockIdx.x * blockDim.x + t;
    int stride = gridDim.x * blockDim.x;
    float s = 0.f;
    const float* ws[5] = {w0, w1, w2, w3, w4};
    int ns[5] = {n0, n1, n2, n3, n4};
    for (int a = 0; a < 5; a++) {
        const float* w = ws[a]; int n = ns[a];
        for (int i = gt; i < n; i += stride) s += fabsf(w[i]);
    }
    sd[t] = s; __syncthreads();
    for (int off = 128; off > 0; off >>= 1) { if (t < off) sd[t] += sd[t + off]; __syncthreads(); }
    if (t == 0) atomicAdd(out, sd[0] * invG);
}

// ================================================================ host side
extern "C" void kernel_launch(void* const* d_in, const int* in_sizes, int n_in,
                              void* d_out, int out_size, void* d_ws, size_t ws_size,
                              hipStream_t stream) {
    const float* node_feat = (const float*)d_in[0];
    const int*   src       = (const int*)d_in[1];
    const int*   dst       = (const int*)d_in[2];
    const int*   seg       = (const int*)d_in[3];
    const float* node_W    = (const float*)d_in[4];
    const float* node_b    = (const float*)d_in[5];
    const float* bn1_g     = (const float*)d_in[6];
    const float* bn1_b     = (const float*)d_in[7];
    const float* conv_W    = (const float*)d_in[8];
    const float* conv_b    = (const float*)d_in[9];
    const float* bn2_g     = (const float*)d_in[10];
    const float* bn2_b     = (const float*)d_in[11];
    const float* k_weight  = (const float*)d_in[12];
    const float* bn3_g     = (const float*)d_in[13];
    const float* bn3_b     = (const float*)d_in[14];
    const float* attn_W1   = (const float*)d_in[15];
    const float* attn_b1   = (const float*)d_in[16];
    const float* bna_g     = (const float*)d_in[17];
    const float* bna_b     = (const float*)d_in[18];
    const float* attn_W2   = (const float*)d_in[19];
    const float* attn_b2   = (const float*)d_in[20];
    const float* bnb_g     = (const float*)d_in[21];
    const float* bnb_b     = (const float*)d_in[22];

    const int N = in_sizes[3];
    const int E = in_sizes[1];
    const int G = (out_size - 1) / 640;
    const int FIN = in_sizes[0] / N;
    const float invN = 1.f / (float)N;

    // ---- workspace layout (all bf16 activations)
    auto align256 = [](size_t x) { return (x + 255) & ~(size_t)255; };
    size_t NB = (size_t)N * D128 * sizeof(bfl);   // 25.6 MB
    char* w = (char*)d_ws;
    bfl* P0 = (bfl*)(w + 0 * NB);   // inp (bn1 out)
    bfl* P1 = (bfl*)(w + 1 * NB);   // bi (block_input)
    bfl* P2 = (bfl*)(w + 2 * NB);   // cur / kgemm accumulator
    bfl* P3 = (bfl*)(w + 3 * NB);   // pooled / attn A
    bfl* P4 = (bfl*)(w + 4 * NB);   // O_k raw
    char* tail = w + 5 * NB;
    size_t off = 0;
    int gemmGrid = (N + 127) / 128;   // 782
    float* stats = (float*)(tail + off); off = align256(off + 15 * 256 * sizeof(float));
    float* part  = (float*)(tail + off); off = align256(off + 8 * 256 * sizeof(float));
    bfl*   wt    = (bfl*)(tail + off);   off = align256(off + 122880 * sizeof(bfl));
    bfl*   wt2   = (bfl*)(tail + off);   off = align256(off + 16384 * sizeof(bfl));
    float* bias2 = (float*)(tail + off); off = align256(off + 128 * sizeof(float));
    float* a2    = (float*)(tail + off); off = align256(off + (size_t)N * 5 * sizeof(float));
    int* deg     = (int*)(tail + off);   off = align256(off + (size_t)N * 4);
    int* rowptr  = (int*)(tail + off);   off = align256(off + (size_t)(N + 1) * 4);
    int* rank    = (int*)(tail + off);   off = align256(off + (size_t)E * 4);
    int* csr_src = (int*)(tail + off);   off = align256(off + (size_t)E * 4);
    int* partials= (int*)(tail + off);   off = align256(off + 512);

    bfl* wt_node = wt;
    bfl* wt_conv = wt + 8192;
    bfl* wt_kw   = wt + 8192 + 49152;
    bfl* wt_attn = wt + 8192 + 98304;
    auto slot = [&](int s) { return stats + (size_t)s * 256; };
    // slots 0..13 hold finalized {sc[128], sh[128]}; slot 14 = raw bnb sums

    int spmmGrid = (N + 3) / 4;

    // ---- zero part accumulator (8 rows), slot14 sums, reg output slot
    hipMemsetAsync(part, 0, 8 * 256 * sizeof(float), stream);
    hipMemsetAsync(slot(14), 0, 256 * sizeof(float), stream);
    hipMemsetAsync((float*)d_out + (size_t)G * 640, 0, 4, stream);

    // ---- CSR build (by dst): one atomic pass + scan + non-atomic place
    hipMemsetAsync(deg, 0, (size_t)N * 4, stream);
    dag_count_rank<<<1024, 256, 0, stream>>>(dst, E, deg, rank);
    int P = (N + 1023) / 1024;
    dag_scan1<<<P, 256, 0, stream>>>(deg, N, rowptr, partials);
    dag_scan2<<<1, 256, 0, stream>>>(partials, P);
    dag_scan3<<<256, 256, 0, stream>>>(rowptr, partials, N, E);
    dag_place<<<1024, 256, 0, stream>>>(src, dst, rank, rowptr, E, csr_src);

    // ---- weights -> bf16 transposed
    dag_wconv<<<480, 256, 0, stream>>>(node_W, conv_W, k_weight, attn_W1, wt);

    // ---- L1 reg (independent)
    dag_reg<<<64, 256, 0, stream>>>(node_W, FIN * D128, conv_W, 3 * D128 * D128,
                                    k_weight, 3 * D128 * D128, attn_W1, D128 * D128,
                                    attn_W2, D128 * 5, (float*)d_out + (size_t)G * 640, 1.0f / G);

    // ---- node embedding: P0 = relu(bn1(node_feat @ node_W + node_b))
    gemm_rw<2, 1, true, false, false, true><<<gemmGrid, 256, 0, stream>>>(
        node_feat, wt_node, node_b, P0, N, part);
    dag_finalize<false><<<1, 256, 0, stream>>>(part, bn1_g, bn1_b, invN,
                                               slot(0), nullptr, nullptr, nullptr);
    dag_bn_apply<true, false><<<2048, 256, 0, stream>>>(P0, slot(0), (size_t)N * D128 / 8,
                                                        nullptr, nullptr);

    // ---- 3 blocks
    for (int blk = 0; blk < 3; blk++) {
        const bfl* bip = (blk == 0) ? P0 : P1;
        for (int k = 0; k < 3; k++) {
            int s2i = 1 + blk * 3 + k;
            // P3 = sc2*spmm_raw(in_x) + cnt*sh2 + bip   (k=0: in_x = bip, no corr)
            const bfl* in_x = (k == 0) ? bip : P4;
            const float* s2 = (k == 0) ? nullptr : slot(s2i - 1);
            dag_spmm<<<spmmGrid, 256, 0, stream>>>(in_x, bip, rowptr, csr_src, P3, N, s2);
            // conv(k): P3 -> P4 (raw; bn2 partials -> part)
            gemm_rw<4, 0, true, false, false, true><<<gemmGrid, 256, 0, stream>>>(
                P3, wt_conv + (size_t)k * 16384, conv_b + k * D128, P4, N, part);
            // finalize bn2 -> slot(s2i) AND build wt2/bias2
            dag_finalize<true><<<1, 256, 0, stream>>>(part,
                                                      bn2_g + k * D128, bn2_b + k * D128, invN,
                                                      slot(s2i), wt_kw + (size_t)k * 16384, wt2, bias2);
            // kw(k): P2 (+)= P4 @ wt2 + bias2; k=2 also writes bn3 partials
            if (k == 0)
                gemm_rw<4, 0, true, false, false, false><<<gemmGrid, 256, 0, stream>>>(
                    P4, wt2, bias2, P2, N, nullptr);
            else if (k == 1)
                gemm_rw<4, 0, true, false, true, false><<<gemmGrid, 256, 0, stream>>>(
                    P4, wt2, bias2, P2, N, nullptr);
            else
                gemm_rw<4, 0, true, false, true, true><<<gemmGrid, 256, 0, stream>>>(
                    P4, wt2, bias2, P2, N, part);
        }
        dag_finalize<false><<<1, 256, 0, stream>>>(part, bn3_g, bn3_b, invN,
                                                   slot(10 + blk), nullptr, nullptr, nullptr);
        // P2 = relu(bn3(P2)); for blk<2 also P1 = P2 + P0
        if (blk < 2)
            dag_bn_apply<true, true><<<2048, 256, 0, stream>>>(P2, slot(10 + blk),
                                                               (size_t)N * D128 / 8, P0, P1);
        else
            dag_bn_apply<true, false><<<2048, 256, 0, stream>>>(P2, slot(10 + blk),
                                                                (size_t)N * D128 / 8, nullptr, nullptr);
    }

    // ---- attention pooling (bna partials from tanh-gemm)
    gemm_rw<4, 0, true, true, false, true><<<gemmGrid, 256, 0, stream>>>(
        P2, wt_attn, attn_b1, P3, N, part);
    dag_finalize<false><<<1, 256, 0, stream>>>(part, bna_g, bna_b, invN,
                                               slot(13), nullptr, nullptr, nullptr);
    dag_gemm5<<<(N + 31) / 32, 256, 0, stream>>>(P3, attn_W2, attn_b2, a2, N, slot(13));
    dag_colstat_f32<<<256, 255, 0, stream>>>(a2, N, 5, slot(14));
    dag_alpha<<<(N + 255) / 256, 256, 0, stream>>>(a2, N, slot(14), bnb_g, bnb_b, invN);
    dag_pool<<<G, 128, 0, stream>>>(a2, P2, seg, N, G, (float*)d_out);
}

// Round 17
// 1243.630 us; speedup vs baseline: 1.2636x; 1.0070x over previous
//
#include <hip/hip_runtime.h>
#include <hip/hip_bf16.h>

#define D128 128
#define EPS 1e-5f

typedef unsigned short bfl;
typedef __bf16 bf16x8 __attribute__((ext_vector_type(8)));
typedef float f32x4 __attribute__((ext_vector_type(4)));

__device__ inline float bf2f(unsigned short u) { return __uint_as_float(((unsigned int)u) << 16); }
__device__ inline unsigned short f2bf(float f) {
    unsigned int x = __float_as_uint(f);
    return (unsigned short)((x + 0x7fffu + ((x >> 16) & 1u)) >> 16);  // RNE
}

// ---------------------------------------------------------------- CSR build
__global__ void dag_count_rank(const int* __restrict__ dst, int E,
                               int* __restrict__ deg, int* __restrict__ rank) {
    int i = blockIdx.x * blockDim.x + threadIdx.x;
    int stride = gridDim.x * blockDim.x;
    for (; i < E; i += stride) {
        int r = atomicAdd(&deg[dst[i]], 1);
        rank[i] = r;
    }
}

__global__ void dag_scan1(const int* __restrict__ deg, int N, int* __restrict__ out, int* __restrict__ partials) {
    __shared__ int sdata[256];
    int t = threadIdx.x;
    int base = blockIdx.x * 1024 + t * 4;
    int v[4]; int s = 0;
#pragma unroll
    for (int j = 0; j < 4; j++) { int idx = base + j; v[j] = (idx < N) ? deg[idx] : 0; s += v[j]; }
    sdata[t] = s; __syncthreads();
    for (int off = 1; off < 256; off <<= 1) {
        int x = (t >= off) ? sdata[t - off] : 0;
        __syncthreads();
        sdata[t] += x;
        __syncthreads();
    }
    int run = (t == 0) ? 0 : sdata[t - 1];
#pragma unroll
    for (int j = 0; j < 4; j++) { int idx = base + j; if (idx < N) out[idx] = run; run += v[j]; }
    if (t == 255) partials[blockIdx.x] = sdata[255];
}

__global__ void dag_scan2(int* __restrict__ partials, int P) {
    __shared__ int sdata[256];
    int t = threadIdx.x;
    int v = (t < P) ? partials[t] : 0;
    sdata[t] = v; __syncthreads();
    for (int off = 1; off < 256; off <<= 1) {
        int x = (t >= off) ? sdata[t - off] : 0;
        __syncthreads();
        sdata[t] += x;
        __syncthreads();
    }
    if (t < P) partials[t] = sdata[t] - v;  // exclusive
}

__global__ void dag_scan3(int* __restrict__ rowptr, const int* __restrict__ partials, int N, int E) {
    int i = blockIdx.x * blockDim.x + threadIdx.x;
    int stride = gridDim.x * blockDim.x;
    for (; i < N; i += stride) rowptr[i] += partials[i >> 10];
    if (blockIdx.x == 0 && threadIdx.x == 0) rowptr[N] = E;
}

__global__ void dag_place(const int* __restrict__ src, const int* __restrict__ dst,
                          const int* __restrict__ rank, const int* __restrict__ rowptr,
                          int E, int* __restrict__ csr_src) {
    int i = blockIdx.x * blockDim.x + threadIdx.x;
    int stride = gridDim.x * blockDim.x;
    for (; i < E; i += stride) {
        csr_src[rowptr[dst[i]] + rank[i]] = src[i];
    }
}

// ------------- weight convert: fp32 row-major -> bf16 transposed ----------
__global__ void dag_wconv(const float* __restrict__ node_W, const float* __restrict__ conv_W,
                          const float* __restrict__ k_weight, const float* __restrict__ attn_W1,
                          bfl* __restrict__ wt) {
    int i = blockIdx.x * blockDim.x + threadIdx.x;
    if (i >= 122880) return;
    float v;
    if (i < 8192) {                       // node_W [64,128] -> [128][64]
        int n = i >> 6, k = i & 63;
        v = node_W[k * 128 + n];
    } else if (i < 8192 + 49152) {        // conv_W [3][128][128] -> 3x[128][128]T
        int j = i - 8192; int k = j >> 14; int r = j & 16383;
        int n = r >> 7, kk = r & 127;
        v = conv_W[k * 16384 + kk * 128 + n];
    } else if (i < 8192 + 98304) {        // k_weight [384,128] -> 3x[128][128]T
        int j = i - 8192 - 49152; int k = j >> 14; int r = j & 16383;
        int n = r >> 7, kk = r & 127;
        v = k_weight[(k * 128 + kk) * 128 + n];
    } else {                              // attn_W1 [128,128] -> [128][128]T
        int j = i - 8192 - 98304;
        int n = j >> 7, kk = j & 127;
        v = attn_W1[kk * 128 + n];
    }
    wt[i] = f2bf(v);
}

// ---- finalize: sum 8 partial rows -> sc/sh; re-zero; optional kw fold ----
template<bool KWPREP>
__global__ void dag_finalize(float* __restrict__ part,
                             const float* __restrict__ g, const float* __restrict__ b,
                             float invN, float* __restrict__ slot,
                             const bfl* __restrict__ WtIn, bfl* __restrict__ Wt2,
                             float* __restrict__ bias2) {
    int t = threadIdx.x;  // 256
    float acc = 0.f;
#pragma unroll
    for (int i = 0; i < 8; i++) acc += part[i * 256 + t];
#pragma unroll
    for (int i = 0; i < 8; i++) part[i * 256 + t] = 0.f;   // ready for next use
    __shared__ float sums[256];
    __shared__ float scs[128], shs[128];
    sums[t] = acc;
    __syncthreads();
    if (t < 128) {
        float m = sums[t] * invN;
        float var = sums[128 + t] * invN - m * m;
        float scale = g[t] * rsqrtf(var + EPS);
        float shift = b[t] - m * scale;
        scs[t] = scale; shs[t] = shift;
        slot[t] = scale; slot[128 + t] = shift;
    }
    if constexpr (KWPREP) {
        __syncthreads();
        int row = t >> 1, half = t & 1;
        const bfl* wr = WtIn + row * 128 + half * 64;
        bfl* w2 = Wt2 + row * 128 + half * 64;
        float a = 0.f;
        for (int k = 0; k < 64; k += 8) {
            bf16x8 v = *(const bf16x8*)(wr + k);
            bfl o[8];
#pragma unroll
            for (int j = 0; j < 8; j++) {
                float f = (float)v[j];
                int kk = half * 64 + k + j;
                a += shs[kk] * f;
                o[j] = f2bf(scs[kk] * f);
            }
            *(bf16x8*)(w2 + k) = *(bf16x8*)o;
        }
        a += __shfl_xor(a, 1);
        if (half == 0) bias2[row] = a;
    }
}

// ----------------- register-weight MFMA GEMM, paired tiles ----------------
template<int KSTEPS, int XMODE, bool BIAS, bool TANH, bool ACC, bool STATS>
__global__ __launch_bounds__(256) void gemm_rw(
        const void* __restrict__ Xv, const bfl* __restrict__ Wt,
        const float* __restrict__ bias, bfl* __restrict__ Y,
        int Nrows, float* __restrict__ partOut) {
    const int Kdim = KSTEPS * 32;
    int t = threadIdx.x;
    int lane = t & 63;
    int wave = t >> 6;
    int cg = wave & 1, rg = wave >> 1;
    int l15 = lane & 15, lg = lane >> 4;

    bf16x8 af[4][KSTEPS];
#pragma unroll
    for (int nf = 0; nf < 4; nf++)
#pragma unroll
        for (int ks = 0; ks < KSTEPS; ks++)
            af[nf][ks] = *(const bf16x8*)(Wt + (size_t)(cg * 64 + nf * 16 + l15) * Kdim + ks * 32 + lg * 8);

    float bia[4][4];
    if (BIAS) {
#pragma unroll
        for (int nf = 0; nf < 4; nf++) {
            float4 bb = *(const float4*)(bias + cg * 64 + nf * 16 + lg * 4);
            bia[nf][0] = bb.x; bia[nf][1] = bb.y; bia[nf][2] = bb.z; bia[nf][3] = bb.w;
        }
    }

    float s_c[4][4], q_c[4][4];
    if constexpr (STATS) {
#pragma unroll
        for (int nf = 0; nf < 4; nf++)
#pragma unroll
            for (int j = 0; j < 4; j++) { s_c[nf][j] = 0.f; q_c[nf][j] = 0.f; }
    }

    const int RT = (Nrows + 15) >> 4;
    const int step = gridDim.x * 2;

    auto load_bf = [&](int rt, bf16x8* bfo) {
        int r = rt * 16 + l15;
        bool valid = (rt < RT) && (r < Nrows);
#pragma unroll
        for (int ks = 0; ks < KSTEPS; ks++) {
            if (valid) {
                if (XMODE == 0) {
                    bfo[ks] = *(const bf16x8*)((const bfl*)Xv + (size_t)r * Kdim + ks * 32 + lg * 8);
                } else {
                    const float* xp = (const float*)Xv + (size_t)r * Kdim + ks * 32 + lg * 8;
                    float4 a4 = *(const float4*)xp;
                    float4 b4 = *(const float4*)(xp + 4);
                    bf16x8 bb;
                    bb[0] = (__bf16)a4.x; bb[1] = (__bf16)a4.y; bb[2] = (__bf16)a4.z; bb[3] = (__bf16)a4.w;
                    bb[4] = (__bf16)b4.x; bb[5] = (__bf16)b4.y; bb[6] = (__bf16)b4.z; bb[7] = (__bf16)b4.w;
                    bfo[ks] = bb;
                }
            } else {
                bf16x8 bb;
#pragma unroll
                for (int j = 0; j < 8; j++) bb[j] = (__bf16)0.f;
                bfo[ks] = bb;
            }
        }
    };

    auto compute_store = [&](int rt, const bf16x8* bfc) {
        int r = rt * 16 + l15;
        bool valid = (rt < RT) && (r < Nrows);
        f32x4 acc[4];
#pragma unroll
        for (int nf = 0; nf < 4; nf++) acc[nf] = (f32x4)0.f;
#pragma unroll
        for (int ks = 0; ks < KSTEPS; ks++)
#pragma unroll
            for (int nf = 0; nf < 4; nf++)
                acc[nf] = __builtin_amdgcn_mfma_f32_16x16x32_bf16(af[nf][ks], bfc[ks], acc[nf], 0, 0, 0);
#pragma unroll
        for (int nf = 0; nf < 4; nf++) {
            int c0 = cg * 64 + nf * 16 + lg * 4;
            f32x4 v = acc[nf];
            if (BIAS) {
#pragma unroll
                for (int j = 0; j < 4; j++) v[j] += bia[nf][j];
            }
            if (TANH) {
#pragma unroll
                for (int j = 0; j < 4; j++) v[j] = tanhf(v[j]);
            }
            if (valid) {
                bfl* yp = Y + (size_t)r * D128 + c0;
                if (ACC) {
                    ushort4 old = *(const ushort4*)yp;
                    v[0] += bf2f(old.x); v[1] += bf2f(old.y); v[2] += bf2f(old.z); v[3] += bf2f(old.w);
                }
                ushort4 o;
                o.x = f2bf(v[0]); o.y = f2bf(v[1]); o.z = f2bf(v[2]); o.w = f2bf(v[3]);
                *(ushort4*)yp = o;
            }
            if constexpr (STATS) {
#pragma unroll
                for (int j = 0; j < 4; j++) {
                    float f = valid ? v[j] : 0.f;
                    s_c[nf][j] += f;
                    q_c[nf][j] += f * f;
                }
            }
        }
    };

    for (int rt = blockIdx.x * 2 + rg; rt < RT; rt += 2 * step) {
        bf16x8 bfA[KSTEPS], bfB[KSTEPS];
        load_bf(rt, bfA);
        load_bf(rt + step, bfB);
        compute_store(rt, bfA);
        compute_store(rt + step, bfB);
    }

    if constexpr (STATS) {
#pragma unroll
        for (int nf = 0; nf < 4; nf++)
#pragma unroll
            for (int j = 0; j < 4; j++) {
                float s = s_c[nf][j], q = q_c[nf][j];
                s += __shfl_xor(s, 1); s += __shfl_xor(s, 2); s += __shfl_xor(s, 4); s += __shfl_xor(s, 8);
                q += __shfl_xor(q, 1); q += __shfl_xor(q, 2); q += __shfl_xor(q, 4); q += __shfl_xor(q, 8);
                s_c[nf][j] = s; q_c[nf][j] = q;
            }
        __shared__ float red[2][2][64];   // [cg][stat][col]
        ((float*)red)[t] = 0.f;
        __syncthreads();
        if (l15 == 0) {
#pragma unroll
            for (int nf = 0; nf < 4; nf++)
#pragma unroll
                for (int j = 0; j < 4; j++) {
                    int c = nf * 16 + lg * 4 + j;
                    atomicAdd(&red[cg][0][c], s_c[nf][j]);   // LDS atomics (block-local)
                    atomicAdd(&red[cg][1][c], q_c[nf][j]);
                }
        }
        __syncthreads();
        int cgi = t >> 7, stat = (t >> 6) & 1, c = t & 63;
        atomicAdd(&partOut[(size_t)(blockIdx.x & 7) * 256 + stat * 128 + cgi * 64 + c],
                  red[cgi][stat][c]);
    }
}

// --------- spmm, wave-per-node, 8-deep unroll -----------------------------
// out = sc*sum(x_raw) + cnt*sh + bi.  8 independent accumulator slots keep
// 8 gathers in flight (mean degree ~8 -> single latency exposure).
__global__ __launch_bounds__(256) void dag_spmm(
        const bfl* __restrict__ x, const bfl* __restrict__ bi,
        const int* __restrict__ rowptr, const int* __restrict__ csr_src,
        bfl* __restrict__ out, int N, const float* __restrict__ scsh) {
    int lane = threadIdx.x & 63;
    int n = blockIdx.x * 4 + (threadIdx.x >> 6);
    if (n >= N) return;
    int c0 = lane * 2;
    float sc0 = 1.f, sc1 = 1.f, sh0 = 0.f, sh1 = 0.f;
    if (scsh) {
        sc0 = scsh[c0];     sh0 = scsh[128 + c0];
        sc1 = scsh[c0 + 1]; sh1 = scsh[128 + c0 + 1];
    }
    int p0 = rowptr[n], p1 = rowptr[n + 1];
    // issue bi load early (independent of the gather chain)
    unsigned int ub = *(const unsigned int*)(bi + (size_t)n * D128 + c0);
    const bfl* xb = x + c0;
    float ax[8], ay[8];
#pragma unroll
    for (int j = 0; j < 8; j++) { ax[j] = 0.f; ay[j] = 0.f; }
    int p = p0;
    for (; p + 8 <= p1; p += 8) {
        unsigned int u[8];
#pragma unroll
        for (int j = 0; j < 8; j++) {
            int s = csr_src[p + j];
            u[j] = *(const unsigned int*)(xb + (size_t)s * D128);
        }
#pragma unroll
        for (int j = 0; j < 8; j++) {
            ax[j] += __uint_as_float(u[j] << 16);
            ay[j] += __uint_as_float(u[j] & 0xffff0000u);
        }
    }
    // remainder (<8): still issue all loads before accumulating
    {
        int rem = p1 - p;
        unsigned int u[8];
#pragma unroll
        for (int j = 0; j < 8; j++) {
            if (j < rem) {
                int s = csr_src[p + j];
                u[j] = *(const unsigned int*)(xb + (size_t)s * D128);
            }
        }
#pragma unroll
        for (int j = 0; j < 8; j++) {
            if (j < rem) {
                ax[j] += __uint_as_float(u[j] << 16);
                ay[j] += __uint_as_float(u[j] & 0xffff0000u);
            }
        }
    }
    float vx = ((ax[0] + ax[1]) + (ax[2] + ax[3])) + ((ax[4] + ax[5]) + (ax[6] + ax[7]));
    float vy = ((ay[0] + ay[1]) + (ay[2] + ay[3])) + ((ay[4] + ay[5]) + (ay[6] + ay[7]));
    float cnt = (float)(p1 - p0);
    vx = sc0 * vx + cnt * sh0 + __uint_as_float(ub << 16);
    vy = sc1 * vy + cnt * sh1 + __uint_as_float(ub & 0xffff0000u);
    unsigned int uo = (unsigned int)f2bf(vx) | ((unsigned int)f2bf(vy) << 16);
    *(unsigned int*)(out + (size_t)n * D128 + c0) = uo;
}

// ----------------- column stats fp32, small C (a2 [N,5]) ------------------
__global__ void dag_colstat_f32(const float* __restrict__ Y, int Nrows, int C, float* __restrict__ sums) {
    __shared__ float ls[8], lss[8];
    int t = threadIdx.x;
    int nlanes = blockDim.x / C;
    int col = t % C, lane = t / C;
    float s = 0.f, ss = 0.f;
    if (lane < nlanes) {
        for (int r = blockIdx.x * nlanes + lane; r < Nrows; r += gridDim.x * nlanes) {
            float v = Y[(size_t)r * C + col];
            s += v; ss += v * v;
        }
    }
    if (t < C) { ls[t] = 0.f; lss[t] = 0.f; }
    __syncthreads();
    if (lane < nlanes) { atomicAdd(&ls[col], s); atomicAdd(&lss[col], ss); }
    __syncthreads();
    if (t < C) { atomicAdd(&sums[t], ls[t]); atomicAdd(&sums[C + t], lss[t]); }
}

// --------- BN apply using finalized sc/sh + optional relu / bi out --------
template<bool RELU, bool ADDOUT>
__global__ void dag_bn_apply(bfl* __restrict__ Y, const float* __restrict__ scsh,
                             size_t n8,
                             const bfl* __restrict__ addin, bfl* __restrict__ out2) {
    __shared__ float sc[128], sh[128];
    int t = threadIdx.x;
    if (t < 128) {
        sc[t] = scsh[t];
        sh[t] = scsh[128 + t];
    }
    __syncthreads();
    for (size_t i = (size_t)blockIdx.x * blockDim.x + t; i < n8; i += (size_t)gridDim.x * blockDim.x) {
        int c0 = (int)((i * 8) & 127);
        bf16x8 v = *(bf16x8*)(Y + i * 8);
        bfl o[8], o2[8];
#pragma unroll
        for (int j = 0; j < 8; j++) {
            float f = (float)v[j] * sc[c0 + j] + sh[c0 + j];
            if (RELU) f = fmaxf(f, 0.f);
            o[j] = f2bf(f);
            if (ADDOUT) o2[j] = f2bf(f + bf2f(addin[i * 8 + j]));
        }
        *(bf16x8*)(Y + i * 8) = *(bf16x8*)o;
        if (ADDOUT) *(bf16x8*)(out2 + i * 8) = *(bf16x8*)o2;
    }
}

// --------------- small GEMM: Y[N,5] = (sc/sh-corrected X) @ W + b ---------
__global__ void dag_gemm5(const bfl* __restrict__ X, const float* __restrict__ W,
                          const float* __restrict__ bias, float* __restrict__ Y, int Nrows,
                          const float* __restrict__ scsh) {
    __shared__ float Xs[32][132];
    __shared__ float Ws[640];
    __shared__ float sc[128], sh[128];
    int t = threadIdx.x;
    if (t < 128) {
        sc[t] = scsh[t];
        sh[t] = scsh[128 + t];
    }
    for (int i = t; i < 640; i += 256) Ws[i] = W[i];
    __syncthreads();
    int row0 = blockIdx.x * 32;
#pragma unroll
    for (int i = 0; i < 2; i++) {
        int off = (i * 256 + t) * 8;
        int r = off >> 7, c = off & 127;
        int gr = row0 + r;
        if (gr < Nrows) {
            bf16x8 v = *(const bf16x8*)(X + (size_t)gr * D128 + c);
#pragma unroll
            for (int j = 0; j < 8; j++) Xs[r][c + j] = (float)v[j] * sc[c + j] + sh[c + j];
        } else {
#pragma unroll
            for (int j = 0; j < 8; j++) Xs[r][c + j] = 0.f;
        }
    }
    __syncthreads();
    if (t < 160) {
        int r = t / 5, h = t % 5;
        int gr = row0 + r;
        if (gr < Nrows) {
            float s = bias[h];
            for (int k = 0; k < 128; k++) s = fmaf(Xs[r][k], Ws[k * 5 + h], s);
            Y[(size_t)gr * 5 + h] = s;
        }
    }
}

// --------------- alpha: in-place bnb + softmax over 5 heads ---------------
__global__ void dag_alpha(float* __restrict__ a2, int N,
                          const float* __restrict__ sums, const float* __restrict__ g,
                          const float* __restrict__ b, float invN) {
    float scb[5], shb[5];
#pragma unroll
    for (int h = 0; h < 5; h++) {
        float s = sums[h], ss = sums[5 + h];
        float m = s * invN;
        float var = ss * invN - m * m;
        float scale = g[h] * rsqrtf(var + EPS);
        scb[h] = scale; shb[h] = b[h] - m * scale;
    }
    int n = blockIdx.x * blockDim.x + threadIdx.x;
    if (n >= N) return;
    float av[5];
    float mx = -1e30f;
#pragma unroll
    for (int h = 0; h < 5; h++) {
        av[h] = a2[(size_t)n * 5 + h] * scb[h] + shb[h];
        mx = fmaxf(mx, av[h]);
    }
    float s = 0.f;
#pragma unroll
    for (int h = 0; h < 5; h++) { av[h] = expf(av[h] - mx); s += av[h]; }
    float inv = 1.f / s;
#pragma unroll
    for (int h = 0; h < 5; h++) a2[(size_t)n * 5 + h] = av[h] * inv;
}

// --------------- attention pooling (alpha precomputed) --------------------
__global__ void dag_pool(const float* __restrict__ alpha, const bfl* __restrict__ emb,
                         const int* __restrict__ seg, int N, int G, float* __restrict__ out) {
    int gg = blockIdx.x;
    int d = threadIdx.x;  // 0..127
    int lo = 0, hi = N;
    while (lo < hi) { int m = (lo + hi) >> 1; if (seg[m] < gg) lo = m + 1; else hi = m; }
    int start = lo;
    lo = start; hi = N;
    while (lo < hi) { int m = (lo + hi) >> 1; if (seg[m] < gg + 1) lo = m + 1; else hi = m; }
    int end = lo;
    float acc[5] = {0.f, 0.f, 0.f, 0.f, 0.f};
    for (int n = start; n < end; n++) {
        float e = bf2f(emb[(size_t)n * D128 + d]);
#pragma unroll
        for (int h = 0; h < 5; h++) acc[h] = fmaf(alpha[(size_t)n * 5 + h], e, acc[h]);
    }
#pragma unroll
    for (int h = 0; h < 5; h++) out[(size_t)gg * 640 + h * D128 + d] = fmaxf(acc[h], 0.f);
}

// --------------- L1 regularizer (multi-block) -----------------------------
__global__ void dag_reg(const float* w0, int n0, const float* w1, int n1, const float* w2, int n2,
                        const float* w3, int n3, const float* w4, int n4, float* out, float invG) {
    __shared__ float sd[256];
    int t = threadIdx.x;
    int gt = blockIdx.x * blockDim.x + t;
    int stride = gridDim.x * blockDim.x;
    float s = 0.f;
    const float* ws[5] = {w0, w1, w2, w3, w4};
    int ns[5] = {n0, n1, n2, n3, n4};
    for (int a = 0; a < 5; a++) {
        const float* w = ws[a]; int n = ns[a];
        for (int i = gt; i < n; i += stride) s += fabsf(w[i]);
    }
    sd[t] = s; __syncthreads();
    for (int off = 128; off > 0; off >>= 1) { if (t < off) sd[t] += sd[t + off]; __syncthreads(); }
    if (t == 0) atomicAdd(out, sd[0] * invG);
}

// ================================================================ host side
extern "C" void kernel_launch(void* const* d_in, const int* in_sizes, int n_in,
                              void* d_out, int out_size, void* d_ws, size_t ws_size,
                              hipStream_t stream) {
    const float* node_feat = (const float*)d_in[0];
    const int*   src       = (const int*)d_in[1];
    const int*   dst       = (const int*)d_in[2];
    const int*   seg       = (const int*)d_in[3];
    const float* node_W    = (const float*)d_in[4];
    const float* node_b    = (const float*)d_in[5];
    const float* bn1_g     = (const float*)d_in[6];
    const float* bn1_b     = (const float*)d_in[7];
    const float* conv_W    = (const float*)d_in[8];
    const float* conv_b    = (const float*)d_in[9];
    const float* bn2_g     = (const float*)d_in[10];
    const float* bn2_b     = (const float*)d_in[11];
    const float* k_weight  = (const float*)d_in[12];
    const float* bn3_g     = (const float*)d_in[13];
    const float* bn3_b     = (const float*)d_in[14];
    const float* attn_W1   = (const float*)d_in[15];
    const float* attn_b1   = (const float*)d_in[16];
    const float* bna_g     = (const float*)d_in[17];
    const float* bna_b     = (const float*)d_in[18];
    const float* attn_W2   = (const float*)d_in[19];
    const float* attn_b2   = (const float*)d_in[20];
    const float* bnb_g     = (const float*)d_in[21];
    const float* bnb_b     = (const float*)d_in[22];

    const int N = in_sizes[3];
    const int E = in_sizes[1];
    const int G = (out_size - 1) / 640;
    const int FIN = in_sizes[0] / N;
    const float invN = 1.f / (float)N;

    // ---- workspace layout (all bf16 activations)
    auto align256 = [](size_t x) { return (x + 255) & ~(size_t)255; };
    size_t NB = (size_t)N * D128 * sizeof(bfl);   // 25.6 MB
    char* w = (char*)d_ws;
    bfl* P0 = (bfl*)(w + 0 * NB);   // inp (bn1 out)
    bfl* P1 = (bfl*)(w + 1 * NB);   // bi (block_input)
    bfl* P2 = (bfl*)(w + 2 * NB);   // cur / kgemm accumulator
    bfl* P3 = (bfl*)(w + 3 * NB);   // pooled / attn A
    bfl* P4 = (bfl*)(w + 4 * NB);   // O_k raw
    char* tail = w + 5 * NB;
    size_t off = 0;
    int gemmGrid = (N + 127) / 128;   // 782
    float* stats = (float*)(tail + off); off = align256(off + 15 * 256 * sizeof(float));
    float* part  = (float*)(tail + off); off = align256(off + 8 * 256 * sizeof(float));
    bfl*   wt    = (bfl*)(tail + off);   off = align256(off + 122880 * sizeof(bfl));
    bfl*   wt2   = (bfl*)(tail + off);   off = align256(off + 16384 * sizeof(bfl));
    float* bias2 = (float*)(tail + off); off = align256(off + 128 * sizeof(float));
    float* a2    = (float*)(tail + off); off = align256(off + (size_t)N * 5 * sizeof(float));
    int* deg     = (int*)(tail + off);   off = align256(off + (size_t)N * 4);
    int* rowptr  = (int*)(tail + off);   off = align256(off + (size_t)(N + 1) * 4);
    int* rank    = (int*)(tail + off);   off = align256(off + (size_t)E * 4);
    int* csr_src = (int*)(tail + off);   off = align256(off + (size_t)E * 4);
    int* partials= (int*)(tail + off);   off = align256(off + 512);

    bfl* wt_node = wt;
    bfl* wt_conv = wt + 8192;
    bfl* wt_kw   = wt + 8192 + 49152;
    bfl* wt_attn = wt + 8192 + 98304;
    auto slot = [&](int s) { return stats + (size_t)s * 256; };
    // slots 0..13 hold finalized {sc[128], sh[128]}; slot 14 = raw bnb sums

    int spmmGrid = (N + 3) / 4;

    // ---- zero part accumulator (8 rows), slot14 sums, reg output slot
    hipMemsetAsync(part, 0, 8 * 256 * sizeof(float), stream);
    hipMemsetAsync(slot(14), 0, 256 * sizeof(float), stream);
    hipMemsetAsync((float*)d_out + (size_t)G * 640, 0, 4, stream);

    // ---- CSR build (by dst): one atomic pass + scan + non-atomic place
    hipMemsetAsync(deg, 0, (size_t)N * 4, stream);
    dag_count_rank<<<1024, 256, 0, stream>>>(dst, E, deg, rank);
    int P = (N + 1023) / 1024;
    dag_scan1<<<P, 256, 0, stream>>>(deg, N, rowptr, partials);
    dag_scan2<<<1, 256, 0, stream>>>(partials, P);
    dag_scan3<<<256, 256, 0, stream>>>(rowptr, partials, N, E);
    dag_place<<<1024, 256, 0, stream>>>(src, dst, rank, rowptr, E, csr_src);

    // ---- weights -> bf16 transposed
    dag_wconv<<<480, 256, 0, stream>>>(node_W, conv_W, k_weight, attn_W1, wt);

    // ---- L1 reg (independent)
    dag_reg<<<64, 256, 0, stream>>>(node_W, FIN * D128, conv_W, 3 * D128 * D128,
                                    k_weight, 3 * D128 * D128, attn_W1, D128 * D128,
                                    attn_W2, D128 * 5, (float*)d_out + (size_t)G * 640, 1.0f / G);

    // ---- node embedding: P0 = relu(bn1(node_feat @ node_W + node_b))
    gemm_rw<2, 1, true, false, false, true><<<gemmGrid, 256, 0, stream>>>(
        node_feat, wt_node, node_b, P0, N, part);
    dag_finalize<false><<<1, 256, 0, stream>>>(part, bn1_g, bn1_b, invN,
                                               slot(0), nullptr, nullptr, nullptr);
    dag_bn_apply<true, false><<<2048, 256, 0, stream>>>(P0, slot(0), (size_t)N * D128 / 8,
                                                        nullptr, nullptr);

    // ---- 3 blocks
    for (int blk = 0; blk < 3; blk++) {
        const bfl* bip = (blk == 0) ? P0 : P1;
        for (int k = 0; k < 3; k++) {
            int s2i = 1 + blk * 3 + k;
            // P3 = sc2*spmm_raw(in_x) + cnt*sh2 + bip   (k=0: in_x = bip, no corr)
            const bfl* in_x = (k == 0) ? bip : P4;
            const float* s2 = (k == 0) ? nullptr : slot(s2i - 1);
            dag_spmm<<<spmmGrid, 256, 0, stream>>>(in_x, bip, rowptr, csr_src, P3, N, s2);
            // conv(k): P3 -> P4 (raw; bn2 partials -> part)
            gemm_rw<4, 0, true, false, false, true><<<gemmGrid, 256, 0, stream>>>(
                P3, wt_conv + (size_t)k * 16384, conv_b + k * D128, P4, N, part);
            // finalize bn2 -> slot(s2i) AND build wt2/bias2
            dag_finalize<true><<<1, 256, 0, stream>>>(part,
                                                      bn2_g + k * D128, bn2_b + k * D128, invN,
                                                      slot(s2i), wt_kw + (size_t)k * 16384, wt2, bias2);
            // kw(k): P2 (+)= P4 @ wt2 + bias2; k=2 also writes bn3 partials
            if (k == 0)
                gemm_rw<4, 0, true, false, false, false><<<gemmGrid, 256, 0, stream>>>(
                    P4, wt2, bias2, P2, N, nullptr);
            else if (k == 1)
                gemm_rw<4, 0, true, false, true, false><<<gemmGrid, 256, 0, stream>>>(
                    P4, wt2, bias2, P2, N, nullptr);
            else
                gemm_rw<4, 0, true, false, true, true><<<gemmGrid, 256, 0, stream>>>(
                    P4, wt2, bias2, P2, N, part);
        }
        dag_finalize<false><<<1, 256, 0, stream>>>(part, bn3_g, bn3_b, invN,
                                                   slot(10 + blk), nullptr, nullptr, nullptr);
        // P2 = relu(bn3(P2)); for blk<2 also P1 = P2 + P0
        if (blk < 2)
            dag_bn_apply<true, true><<<2048, 256, 0, stream>>>(P2, slot(10 + blk),
                                                               (size_t)N * D128 / 8, P0, P1);
        else
            dag_bn_apply<true, false><<<2048, 256, 0, stream>>>(P2, slot(10 + blk),
                                                                (size_t)N * D128 / 8, nullptr, nullptr);
    }

    // ---- attention pooling (bna partials from tanh-gemm)
    gemm_rw<4, 0, true, true, false, true><<<gemmGrid, 256, 0, stream>>>(
        P2, wt_attn, attn_b1, P3, N, part);
    dag_finalize<false><<<1, 256, 0, stream>>>(part, bna_g, bna_b, invN,
                                               slot(13), nullptr, nullptr, nullptr);
    dag_gemm5<<<(N + 31) / 32, 256, 0, stream>>>(P3, attn_W2, attn_b2, a2, N, slot(13));
    dag_colstat_f32<<<256, 255, 0, stream>>>(a2, N, 5, slot(14));
    dag_alpha<<<(N + 255) / 256, 256, 0, stream>>>(a2, N, slot(14), bnb_g, bnb_b, invN);
    dag_pool<<<G, 128, 0, stream>>>(a2, P2, seg, N, G, (float*)d_out);
}

// Round 18
// 1158.060 us; speedup vs baseline: 1.3569x; 1.0739x over previous
//
#include <hip/hip_runtime.h>
#include <hip/hip_bf16.h>

#define D128 128
#define EPS 1e-5f

typedef unsigned short bfl;
typedef __bf16 bf16x8 __attribute__((ext_vector_type(8)));
typedef float f32x4 __attribute__((ext_vector_type(4)));

__device__ inline float bf2f(unsigned short u) { return __uint_as_float(((unsigned int)u) << 16); }
__device__ inline unsigned short f2bf(float f) {
    unsigned int x = __float_as_uint(f);
    return (unsigned short)((x + 0x7fffu + ((x >> 16) & 1u)) >> 16);  // RNE
}

// ---------------------------------------------------------------- CSR build
__global__ void dag_count_rank(const int* __restrict__ dst, int E,
                               int* __restrict__ deg, int* __restrict__ rank) {
    int i = blockIdx.x * blockDim.x + threadIdx.x;
    int stride = gridDim.x * blockDim.x;
    for (; i < E; i += stride) {
        int r = atomicAdd(&deg[dst[i]], 1);
        rank[i] = r;
    }
}

__global__ void dag_scan1(const int* __restrict__ deg, int N, int* __restrict__ out, int* __restrict__ partials) {
    __shared__ int sdata[256];
    int t = threadIdx.x;
    int base = blockIdx.x * 1024 + t * 4;
    int v[4]; int s = 0;
#pragma unroll
    for (int j = 0; j < 4; j++) { int idx = base + j; v[j] = (idx < N) ? deg[idx] : 0; s += v[j]; }
    sdata[t] = s; __syncthreads();
    for (int off = 1; off < 256; off <<= 1) {
        int x = (t >= off) ? sdata[t - off] : 0;
        __syncthreads();
        sdata[t] += x;
        __syncthreads();
    }
    int run = (t == 0) ? 0 : sdata[t - 1];
#pragma unroll
    for (int j = 0; j < 4; j++) { int idx = base + j; if (idx < N) out[idx] = run; run += v[j]; }
    if (t == 255) partials[blockIdx.x] = sdata[255];
}

__global__ void dag_scan2(int* __restrict__ partials, int P) {
    __shared__ int sdata[256];
    int t = threadIdx.x;
    int v = (t < P) ? partials[t] : 0;
    sdata[t] = v; __syncthreads();
    for (int off = 1; off < 256; off <<= 1) {
        int x = (t >= off) ? sdata[t - off] : 0;
        __syncthreads();
        sdata[t] += x;
        __syncthreads();
    }
    if (t < P) partials[t] = sdata[t] - v;  // exclusive
}

__global__ void dag_scan3(int* __restrict__ rowptr, const int* __restrict__ partials, int N, int E) {
    int i = blockIdx.x * blockDim.x + threadIdx.x;
    int stride = gridDim.x * blockDim.x;
    for (; i < N; i += stride) rowptr[i] += partials[i >> 10];
    if (blockIdx.x == 0 && threadIdx.x == 0) rowptr[N] = E;
}

__global__ void dag_place(const int* __restrict__ src, const int* __restrict__ dst,
                          const int* __restrict__ rank, const int* __restrict__ rowptr,
                          int E, int* __restrict__ csr_src) {
    int i = blockIdx.x * blockDim.x + threadIdx.x;
    int stride = gridDim.x * blockDim.x;
    for (; i < E; i += stride) {
        csr_src[rowptr[dst[i]] + rank[i]] = src[i];
    }
}

// ------------- weight convert: fp32 row-major -> bf16 transposed ----------
__global__ void dag_wconv(const float* __restrict__ node_W, const float* __restrict__ conv_W,
                          const float* __restrict__ k_weight, const float* __restrict__ attn_W1,
                          bfl* __restrict__ wt) {
    int i = blockIdx.x * blockDim.x + threadIdx.x;
    if (i >= 122880) return;
    float v;
    if (i < 8192) {                       // node_W [64,128] -> [128][64]
        int n = i >> 6, k = i & 63;
        v = node_W[k * 128 + n];
    } else if (i < 8192 + 49152) {        // conv_W [3][128][128] -> 3x[128][128]T
        int j = i - 8192; int k = j >> 14; int r = j & 16383;
        int n = r >> 7, kk = r & 127;
        v = conv_W[k * 16384 + kk * 128 + n];
    } else if (i < 8192 + 98304) {        // k_weight [384,128] -> 3x[128][128]T
        int j = i - 8192 - 49152; int k = j >> 14; int r = j & 16383;
        int n = r >> 7, kk = r & 127;
        v = k_weight[(k * 128 + kk) * 128 + n];
    } else {                              // attn_W1 [128,128] -> [128][128]T
        int j = i - 8192 - 98304;
        int n = j >> 7, kk = j & 127;
        v = attn_W1[kk * 128 + n];
    }
    wt[i] = f2bf(v);
}

// ---- finalize: sum 8 partial rows -> sc/sh; re-zero; optional kw fold ----
template<bool KWPREP>
__global__ void dag_finalize(float* __restrict__ part,
                             const float* __restrict__ g, const float* __restrict__ b,
                             float invN, float* __restrict__ slot,
                             const bfl* __restrict__ WtIn, bfl* __restrict__ Wt2,
                             float* __restrict__ bias2) {
    int t = threadIdx.x;  // 256
    float acc = 0.f;
#pragma unroll
    for (int i = 0; i < 8; i++) acc += part[i * 256 + t];
#pragma unroll
    for (int i = 0; i < 8; i++) part[i * 256 + t] = 0.f;   // ready for next use
    __shared__ float sums[256];
    __shared__ float scs[128], shs[128];
    sums[t] = acc;
    __syncthreads();
    if (t < 128) {
        float m = sums[t] * invN;
        float var = sums[128 + t] * invN - m * m;
        float scale = g[t] * rsqrtf(var + EPS);
        float shift = b[t] - m * scale;
        scs[t] = scale; shs[t] = shift;
        slot[t] = scale; slot[128 + t] = shift;
    }
    if constexpr (KWPREP) {
        __syncthreads();
        int row = t >> 1, half = t & 1;
        const bfl* wr = WtIn + row * 128 + half * 64;
        bfl* w2 = Wt2 + row * 128 + half * 64;
        float a = 0.f;
        for (int k = 0; k < 64; k += 8) {
            bf16x8 v = *(const bf16x8*)(wr + k);
            bfl o[8];
#pragma unroll
            for (int j = 0; j < 8; j++) {
                float f = (float)v[j];
                int kk = half * 64 + k + j;
                a += shs[kk] * f;
                o[j] = f2bf(scs[kk] * f);
            }
            *(bf16x8*)(w2 + k) = *(bf16x8*)o;
        }
        a += __shfl_xor(a, 1);
        if (half == 0) bias2[row] = a;
    }
}

// ----------------- register-weight MFMA GEMM, paired tiles ----------------
template<int KSTEPS, int XMODE, bool BIAS, bool TANH, bool ACC, bool STATS>
__global__ __launch_bounds__(256) void gemm_rw(
        const void* __restrict__ Xv, const bfl* __restrict__ Wt,
        const float* __restrict__ bias, bfl* __restrict__ Y,
        int Nrows, float* __restrict__ partOut) {
    const int Kdim = KSTEPS * 32;
    int t = threadIdx.x;
    int lane = t & 63;
    int wave = t >> 6;
    int cg = wave & 1, rg = wave >> 1;
    int l15 = lane & 15, lg = lane >> 4;

    bf16x8 af[4][KSTEPS];
#pragma unroll
    for (int nf = 0; nf < 4; nf++)
#pragma unroll
        for (int ks = 0; ks < KSTEPS; ks++)
            af[nf][ks] = *(const bf16x8*)(Wt + (size_t)(cg * 64 + nf * 16 + l15) * Kdim + ks * 32 + lg * 8);

    float bia[4][4];
    if (BIAS) {
#pragma unroll
        for (int nf = 0; nf < 4; nf++) {
            float4 bb = *(const float4*)(bias + cg * 64 + nf * 16 + lg * 4);
            bia[nf][0] = bb.x; bia[nf][1] = bb.y; bia[nf][2] = bb.z; bia[nf][3] = bb.w;
        }
    }

    float s_c[4][4], q_c[4][4];
    if constexpr (STATS) {
#pragma unroll
        for (int nf = 0; nf < 4; nf++)
#pragma unroll
            for (int j = 0; j < 4; j++) { s_c[nf][j] = 0.f; q_c[nf][j] = 0.f; }
    }

    const int RT = (Nrows + 15) >> 4;
    const int step = gridDim.x * 2;

    auto load_bf = [&](int rt, bf16x8* bfo) {
        int r = rt * 16 + l15;
        bool valid = (rt < RT) && (r < Nrows);
#pragma unroll
        for (int ks = 0; ks < KSTEPS; ks++) {
            if (valid) {
                if (XMODE == 0) {
                    bfo[ks] = *(const bf16x8*)((const bfl*)Xv + (size_t)r * Kdim + ks * 32 + lg * 8);
                } else {
                    const float* xp = (const float*)Xv + (size_t)r * Kdim + ks * 32 + lg * 8;
                    float4 a4 = *(const float4*)xp;
                    float4 b4 = *(const float4*)(xp + 4);
                    bf16x8 bb;
                    bb[0] = (__bf16)a4.x; bb[1] = (__bf16)a4.y; bb[2] = (__bf16)a4.z; bb[3] = (__bf16)a4.w;
                    bb[4] = (__bf16)b4.x; bb[5] = (__bf16)b4.y; bb[6] = (__bf16)b4.z; bb[7] = (__bf16)b4.w;
                    bfo[ks] = bb;
                }
            } else {
                bf16x8 bb;
#pragma unroll
                for (int j = 0; j < 8; j++) bb[j] = (__bf16)0.f;
                bfo[ks] = bb;
            }
        }
    };

    auto compute_store = [&](int rt, const bf16x8* bfc) {
        int r = rt * 16 + l15;
        bool valid = (rt < RT) && (r < Nrows);
        f32x4 acc[4];
#pragma unroll
        for (int nf = 0; nf < 4; nf++) acc[nf] = (f32x4)0.f;
#pragma unroll
        for (int ks = 0; ks < KSTEPS; ks++)
#pragma unroll
            for (int nf = 0; nf < 4; nf++)
                acc[nf] = __builtin_amdgcn_mfma_f32_16x16x32_bf16(af[nf][ks], bfc[ks], acc[nf], 0, 0, 0);
#pragma unroll
        for (int nf = 0; nf < 4; nf++) {
            int c0 = cg * 64 + nf * 16 + lg * 4;
            f32x4 v = acc[nf];
            if (BIAS) {
#pragma unroll
                for (int j = 0; j < 4; j++) v[j] += bia[nf][j];
            }
            if (TANH) {
#pragma unroll
                for (int j = 0; j < 4; j++) v[j] = tanhf(v[j]);
            }
            if (valid) {
                bfl* yp = Y + (size_t)r * D128 + c0;
                if (ACC) {
                    ushort4 old = *(const ushort4*)yp;
                    v[0] += bf2f(old.x); v[1] += bf2f(old.y); v[2] += bf2f(old.z); v[3] += bf2f(old.w);
                }
                ushort4 o;
                o.x = f2bf(v[0]); o.y = f2bf(v[1]); o.z = f2bf(v[2]); o.w = f2bf(v[3]);
                *(ushort4*)yp = o;
            }
            if constexpr (STATS) {
#pragma unroll
                for (int j = 0; j < 4; j++) {
                    float f = valid ? v[j] : 0.f;
                    s_c[nf][j] += f;
                    q_c[nf][j] += f * f;
                }
            }
        }
    };

    for (int rt = blockIdx.x * 2 + rg; rt < RT; rt += 2 * step) {
        bf16x8 bfA[KSTEPS], bfB[KSTEPS];
        load_bf(rt, bfA);
        load_bf(rt + step, bfB);
        compute_store(rt, bfA);
        compute_store(rt + step, bfB);
    }

    if constexpr (STATS) {
#pragma unroll
        for (int nf = 0; nf < 4; nf++)
#pragma unroll
            for (int j = 0; j < 4; j++) {
                float s = s_c[nf][j], q = q_c[nf][j];
                s += __shfl_xor(s, 1); s += __shfl_xor(s, 2); s += __shfl_xor(s, 4); s += __shfl_xor(s, 8);
                q += __shfl_xor(q, 1); q += __shfl_xor(q, 2); q += __shfl_xor(q, 4); q += __shfl_xor(q, 8);
                s_c[nf][j] = s; q_c[nf][j] = q;
            }
        __shared__ float red[2][2][64];   // [cg][stat][col]
        ((float*)red)[t] = 0.f;
        __syncthreads();
        if (l15 == 0) {
#pragma unroll
            for (int nf = 0; nf < 4; nf++)
#pragma unroll
                for (int j = 0; j < 4; j++) {
                    int c = nf * 16 + lg * 4 + j;
                    atomicAdd(&red[cg][0][c], s_c[nf][j]);   // LDS atomics (block-local)
                    atomicAdd(&red[cg][1][c], q_c[nf][j]);
                }
        }
        __syncthreads();
        int cgi = t >> 7, stat = (t >> 6) & 1, c = t & 63;
        atomicAdd(&partOut[(size_t)(blockIdx.x & 7) * 256 + stat * 128 + cgi * 64 + c],
                  red[cgi][stat][c]);
    }
}

// --------- spmm, 4 nodes per wave: 16 lanes x 16B per node ---------------
// out = sc*sum(x_raw) + cnt*sh + bi.  Gather instructions per node drop
// ~2.8x vs wave-per-node; bi/out accesses are 1KB contiguous per wave.
__global__ __launch_bounds__(256) void dag_spmm(
        const bfl* __restrict__ x, const bfl* __restrict__ bi,
        const int* __restrict__ rowptr, const int* __restrict__ csr_src,
        bfl* __restrict__ out, int N, const float* __restrict__ scsh) {
    int t = threadIdx.x;
    int lane = t & 63;
    int wave = t >> 6;
    int l16 = lane & 15;
    int sub = lane >> 4;                  // node within wave (0..3)
    int c0 = l16 * 8;                     // bf16 column (8 cols = 16B per lane)
    int n = blockIdx.x * 16 + wave * 4 + sub;
    bool valid = n < N;

    float sc[8], sh[8];
    if (scsh) {
        float4 a = *(const float4*)(scsh + c0);
        float4 b = *(const float4*)(scsh + c0 + 4);
        float4 p = *(const float4*)(scsh + 128 + c0);
        float4 q = *(const float4*)(scsh + 128 + c0 + 4);
        sc[0] = a.x; sc[1] = a.y; sc[2] = a.z; sc[3] = a.w;
        sc[4] = b.x; sc[5] = b.y; sc[6] = b.z; sc[7] = b.w;
        sh[0] = p.x; sh[1] = p.y; sh[2] = p.z; sh[3] = p.w;
        sh[4] = q.x; sh[5] = q.y; sh[6] = q.z; sh[7] = q.w;
    } else {
#pragma unroll
        for (int j = 0; j < 8; j++) { sc[j] = 1.f; sh[j] = 0.f; }
    }

    int p0 = valid ? rowptr[n] : 0;
    int p1 = valid ? rowptr[n + 1] : 0;
    int deg = p1 - p0;
    // wave-max degree (subs differ on lane bits 4,5)
    int md = deg;
    md = max(md, __shfl_xor(md, 16));
    md = max(md, __shfl_xor(md, 32));

    // bi early (independent)
    uint4 ub = make_uint4(0, 0, 0, 0);
    if (valid) ub = *(const uint4*)(bi + (size_t)n * D128 + c0);

    const bfl* xb = x + c0;
    float acc[8];
#pragma unroll
    for (int j = 0; j < 8; j++) acc[j] = 0.f;

    for (int j = 0; j < md; j += 4) {
        uint4 u[4];
#pragma unroll
        for (int r = 0; r < 4; r++) {
            u[r] = make_uint4(0, 0, 0, 0);
            if (j + r < deg) {
                int s = csr_src[p0 + j + r];
                u[r] = *(const uint4*)(xb + (size_t)s * D128);
            }
        }
#pragma unroll
        for (int r = 0; r < 4; r++) {
            acc[0] += __uint_as_float(u[r].x << 16);
            acc[1] += __uint_as_float(u[r].x & 0xffff0000u);
            acc[2] += __uint_as_float(u[r].y << 16);
            acc[3] += __uint_as_float(u[r].y & 0xffff0000u);
            acc[4] += __uint_as_float(u[r].z << 16);
            acc[5] += __uint_as_float(u[r].z & 0xffff0000u);
            acc[6] += __uint_as_float(u[r].w << 16);
            acc[7] += __uint_as_float(u[r].w & 0xffff0000u);
        }
    }

    if (valid) {
        float cnt = (float)deg;
        float bv[8];
        bv[0] = __uint_as_float(ub.x << 16); bv[1] = __uint_as_float(ub.x & 0xffff0000u);
        bv[2] = __uint_as_float(ub.y << 16); bv[3] = __uint_as_float(ub.y & 0xffff0000u);
        bv[4] = __uint_as_float(ub.z << 16); bv[5] = __uint_as_float(ub.z & 0xffff0000u);
        bv[6] = __uint_as_float(ub.w << 16); bv[7] = __uint_as_float(ub.w & 0xffff0000u);
        float v[8];
#pragma unroll
        for (int j = 0; j < 8; j++) v[j] = sc[j] * acc[j] + cnt * sh[j] + bv[j];
        uint4 o;
        o.x = (unsigned int)f2bf(v[0]) | ((unsigned int)f2bf(v[1]) << 16);
        o.y = (unsigned int)f2bf(v[2]) | ((unsigned int)f2bf(v[3]) << 16);
        o.z = (unsigned int)f2bf(v[4]) | ((unsigned int)f2bf(v[5]) << 16);
        o.w = (unsigned int)f2bf(v[6]) | ((unsigned int)f2bf(v[7]) << 16);
        *(uint4*)(out + (size_t)n * D128 + c0) = o;
    }
}

// ----------------- column stats fp32, small C (a2 [N,5]) ------------------
__global__ void dag_colstat_f32(const float* __restrict__ Y, int Nrows, int C, float* __restrict__ sums) {
    __shared__ float ls[8], lss[8];
    int t = threadIdx.x;
    int nlanes = blockDim.x / C;
    int col = t % C, lane = t / C;
    float s = 0.f, ss = 0.f;
    if (lane < nlanes) {
        for (int r = blockIdx.x * nlanes + lane; r < Nrows; r += gridDim.x * nlanes) {
            float v = Y[(size_t)r * C + col];
            s += v; ss += v * v;
        }
    }
    if (t < C) { ls[t] = 0.f; lss[t] = 0.f; }
    __syncthreads();
    if (lane < nlanes) { atomicAdd(&ls[col], s); atomicAdd(&lss[col], ss); }
    __syncthreads();
    if (t < C) { atomicAdd(&sums[t], ls[t]); atomicAdd(&sums[C + t], lss[t]); }
}

// --------- BN apply using finalized sc/sh; WRITEY=false skips Y store -----
template<bool RELU, bool ADDOUT, bool WRITEY>
__global__ void dag_bn_apply(bfl* __restrict__ Y, const float* __restrict__ scsh,
                             size_t n8,
                             const bfl* __restrict__ addin, bfl* __restrict__ out2) {
    __shared__ float sc[128], sh[128];
    int t = threadIdx.x;
    if (t < 128) {
        sc[t] = scsh[t];
        sh[t] = scsh[128 + t];
    }
    __syncthreads();
    for (size_t i = (size_t)blockIdx.x * blockDim.x + t; i < n8; i += (size_t)gridDim.x * blockDim.x) {
        int c0 = (int)((i * 8) & 127);
        bf16x8 v = *(bf16x8*)(Y + i * 8);
        bfl o[8], o2[8];
#pragma unroll
        for (int j = 0; j < 8; j++) {
            float f = (float)v[j] * sc[c0 + j] + sh[c0 + j];
            if (RELU) f = fmaxf(f, 0.f);
            o[j] = f2bf(f);
            if (ADDOUT) o2[j] = f2bf(f + bf2f(addin[i * 8 + j]));
        }
        if (WRITEY) *(bf16x8*)(Y + i * 8) = *(bf16x8*)o;
        if (ADDOUT) *(bf16x8*)(out2 + i * 8) = *(bf16x8*)o2;
    }
}

// --------------- small GEMM: Y[N,5] = (sc/sh-corrected X) @ W + b ---------
__global__ void dag_gemm5(const bfl* __restrict__ X, const float* __restrict__ W,
                          const float* __restrict__ bias, float* __restrict__ Y, int Nrows,
                          const float* __restrict__ scsh) {
    __shared__ float Xs[32][132];
    __shared__ float Ws[640];
    __shared__ float sc[128], sh[128];
    int t = threadIdx.x;
    if (t < 128) {
        sc[t] = scsh[t];
        sh[t] = scsh[128 + t];
    }
    for (int i = t; i < 640; i += 256) Ws[i] = W[i];
    __syncthreads();
    int row0 = blockIdx.x * 32;
#pragma unroll
    for (int i = 0; i < 2; i++) {
        int off = (i * 256 + t) * 8;
        int r = off >> 7, c = off & 127;
        int gr = row0 + r;
        if (gr < Nrows) {
            bf16x8 v = *(const bf16x8*)(X + (size_t)gr * D128 + c);
#pragma unroll
            for (int j = 0; j < 8; j++) Xs[r][c + j] = (float)v[j] * sc[c + j] + sh[c + j];
        } else {
#pragma unroll
            for (int j = 0; j < 8; j++) Xs[r][c + j] = 0.f;
        }
    }
    __syncthreads();
    if (t < 160) {
        int r = t / 5, h = t % 5;
        int gr = row0 + r;
        if (gr < Nrows) {
            float s = bias[h];
            for (int k = 0; k < 128; k++) s = fmaf(Xs[r][k], Ws[k * 5 + h], s);
            Y[(size_t)gr * 5 + h] = s;
        }
    }
}

// --------------- alpha: in-place bnb + softmax over 5 heads ---------------
__global__ void dag_alpha(float* __restrict__ a2, int N,
                          const float* __restrict__ sums, const float* __restrict__ g,
                          const float* __restrict__ b, float invN) {
    float scb[5], shb[5];
#pragma unroll
    for (int h = 0; h < 5; h++) {
        float s = sums[h], ss = sums[5 + h];
        float m = s * invN;
        float var = ss * invN - m * m;
        float scale = g[h] * rsqrtf(var + EPS);
        scb[h] = scale; shb[h] = b[h] - m * scale;
    }
    int n = blockIdx.x * blockDim.x + threadIdx.x;
    if (n >= N) return;
    float av[5];
    float mx = -1e30f;
#pragma unroll
    for (int h = 0; h < 5; h++) {
        av[h] = a2[(size_t)n * 5 + h] * scb[h] + shb[h];
        mx = fmaxf(mx, av[h]);
    }
    float s = 0.f;
#pragma unroll
    for (int h = 0; h < 5; h++) { av[h] = expf(av[h] - mx); s += av[h]; }
    float inv = 1.f / s;
#pragma unroll
    for (int h = 0; h < 5; h++) a2[(size_t)n * 5 + h] = av[h] * inv;
}

// --------------- attention pooling (alpha precomputed) --------------------
__global__ void dag_pool(const float* __restrict__ alpha, const bfl* __restrict__ emb,
                         const int* __restrict__ seg, int N, int G, float* __restrict__ out) {
    int gg = blockIdx.x;
    int d = threadIdx.x;  // 0..127
    int lo = 0, hi = N;
    while (lo < hi) { int m = (lo + hi) >> 1; if (seg[m] < gg) lo = m + 1; else hi = m; }
    int start = lo;
    lo = start; hi = N;
    while (lo < hi) { int m = (lo + hi) >> 1; if (seg[m] < gg + 1) lo = m + 1; else hi = m; }
    int end = lo;
    float acc[5] = {0.f, 0.f, 0.f, 0.f, 0.f};
    for (int n = start; n < end; n++) {
        float e = bf2f(emb[(size_t)n * D128 + d]);
#pragma unroll
        for (int h = 0; h < 5; h++) acc[h] = fmaf(alpha[(size_t)n * 5 + h], e, acc[h]);
    }
#pragma unroll
    for (int h = 0; h < 5; h++) out[(size_t)gg * 640 + h * D128 + d] = fmaxf(acc[h], 0.f);
}

// --------------- L1 regularizer (multi-block) -----------------------------
__global__ void dag_reg(const float* w0, int n0, const float* w1, int n1, const float* w2, int n2,
                        const float* w3, int n3, const float* w4, int n4, float* out, float invG) {
    __shared__ float sd[256];
    int t = threadIdx.x;
    int gt = blockIdx.x * blockDim.x + t;
    int stride = gridDim.x * blockDim.x;
    float s = 0.f;
    const float* ws[5] = {w0, w1, w2, w3, w4};
    int ns[5] = {n0, n1, n2, n3, n4};
    for (int a = 0; a < 5; a++) {
        const float* w = ws[a]; int n = ns[a];
        for (int i = gt; i < n; i += stride) s += fabsf(w[i]);
    }
    sd[t] = s; __syncthreads();
    for (int off = 128; off > 0; off >>= 1) { if (t < off) sd[t] += sd[t + off]; __syncthreads(); }
    if (t == 0) atomicAdd(out, sd[0] * invG);
}

// ================================================================ host side
extern "C" void kernel_launch(void* const* d_in, const int* in_sizes, int n_in,
                              void* d_out, int out_size, void* d_ws, size_t ws_size,
                              hipStream_t stream) {
    const float* node_feat = (const float*)d_in[0];
    const int*   src       = (const int*)d_in[1];
    const int*   dst       = (const int*)d_in[2];
    const int*   seg       = (const int*)d_in[3];
    const float* node_W    = (const float*)d_in[4];
    const float* node_b    = (const float*)d_in[5];
    const float* bn1_g     = (const float*)d_in[6];
    const float* bn1_b     = (const float*)d_in[7];
    const float* conv_W    = (const float*)d_in[8];
    const float* conv_b    = (const float*)d_in[9];
    const float* bn2_g     = (const float*)d_in[10];
    const float* bn2_b     = (const float*)d_in[11];
    const float* k_weight  = (const float*)d_in[12];
    const float* bn3_g     = (const float*)d_in[13];
    const float* bn3_b     = (const float*)d_in[14];
    const float* attn_W1   = (const float*)d_in[15];
    const float* attn_b1   = (const float*)d_in[16];
    const float* bna_g     = (const float*)d_in[17];
    const float* bna_b     = (const float*)d_in[18];
    const float* attn_W2   = (const float*)d_in[19];
    const float* attn_b2   = (const float*)d_in[20];
    const float* bnb_g     = (const float*)d_in[21];
    const float* bnb_b     = (const float*)d_in[22];

    const int N = in_sizes[3];
    const int E = in_sizes[1];
    const int G = (out_size - 1) / 640;
    const int FIN = in_sizes[0] / N;
    const float invN = 1.f / (float)N;

    // ---- workspace layout (all bf16 activations)
    auto align256 = [](size_t x) { return (x + 255) & ~(size_t)255; };
    size_t NB = (size_t)N * D128 * sizeof(bfl);   // 25.6 MB
    char* w = (char*)d_ws;
    bfl* P0 = (bfl*)(w + 0 * NB);   // inp (bn1 out)
    bfl* P1 = (bfl*)(w + 1 * NB);   // bi (block_input)
    bfl* P2 = (bfl*)(w + 2 * NB);   // cur / kgemm accumulator
    bfl* P3 = (bfl*)(w + 3 * NB);   // pooled / attn A
    bfl* P4 = (bfl*)(w + 4 * NB);   // O_k raw
    char* tail = w + 5 * NB;
    size_t off = 0;
    int gemmGrid = (N + 127) / 128;   // 782
    float* stats = (float*)(tail + off); off = align256(off + 15 * 256 * sizeof(float));
    float* part  = (float*)(tail + off); off = align256(off + 8 * 256 * sizeof(float));
    bfl*   wt    = (bfl*)(tail + off);   off = align256(off + 122880 * sizeof(bfl));
    bfl*   wt2   = (bfl*)(tail + off);   off = align256(off + 16384 * sizeof(bfl));
    float* bias2 = (float*)(tail + off); off = align256(off + 128 * sizeof(float));
    float* a2    = (float*)(tail + off); off = align256(off + (size_t)N * 5 * sizeof(float));
    int* deg     = (int*)(tail + off);   off = align256(off + (size_t)N * 4);
    int* rowptr  = (int*)(tail + off);   off = align256(off + (size_t)(N + 1) * 4);
    int* rank    = (int*)(tail + off);   off = align256(off + (size_t)E * 4);
    int* csr_src = (int*)(tail + off);   off = align256(off + (size_t)E * 4);
    int* partials= (int*)(tail + off);   off = align256(off + 512);

    bfl* wt_node = wt;
    bfl* wt_conv = wt + 8192;
    bfl* wt_kw   = wt + 8192 + 49152;
    bfl* wt_attn = wt + 8192 + 98304;
    auto slot = [&](int s) { return stats + (size_t)s * 256; };
    // slots 0..13 hold finalized {sc[128], sh[128]}; slot 14 = raw bnb sums

    int spmmGrid = (N + 15) / 16;   // 4 nodes per wave, 4 waves per block

    // ---- zero part accumulator (8 rows), slot14 sums, reg output slot
    hipMemsetAsync(part, 0, 8 * 256 * sizeof(float), stream);
    hipMemsetAsync(slot(14), 0, 256 * sizeof(float), stream);
    hipMemsetAsync((float*)d_out + (size_t)G * 640, 0, 4, stream);

    // ---- CSR build (by dst): one atomic pass + scan + non-atomic place
    hipMemsetAsync(deg, 0, (size_t)N * 4, stream);
    dag_count_rank<<<1024, 256, 0, stream>>>(dst, E, deg, rank);
    int P = (N + 1023) / 1024;
    dag_scan1<<<P, 256, 0, stream>>>(deg, N, rowptr, partials);
    dag_scan2<<<1, 256, 0, stream>>>(partials, P);
    dag_scan3<<<256, 256, 0, stream>>>(rowptr, partials, N, E);
    dag_place<<<1024, 256, 0, stream>>>(src, dst, rank, rowptr, E, csr_src);

    // ---- weights -> bf16 transposed
    dag_wconv<<<480, 256, 0, stream>>>(node_W, conv_W, k_weight, attn_W1, wt);

    // ---- L1 reg (independent)
    dag_reg<<<64, 256, 0, stream>>>(node_W, FIN * D128, conv_W, 3 * D128 * D128,
                                    k_weight, 3 * D128 * D128, attn_W1, D128 * D128,
                                    attn_W2, D128 * 5, (float*)d_out + (size_t)G * 640, 1.0f / G);

    // ---- node embedding: P0 = relu(bn1(node_feat @ node_W + node_b))
    gemm_rw<2, 1, true, false, false, true><<<gemmGrid, 256, 0, stream>>>(
        node_feat, wt_node, node_b, P0, N, part);
    dag_finalize<false><<<1, 256, 0, stream>>>(part, bn1_g, bn1_b, invN,
                                               slot(0), nullptr, nullptr, nullptr);
    dag_bn_apply<true, false, true><<<2048, 256, 0, stream>>>(P0, slot(0), (size_t)N * D128 / 8,
                                                              nullptr, nullptr);

    // ---- 3 blocks
    for (int blk = 0; blk < 3; blk++) {
        const bfl* bip = (blk == 0) ? P0 : P1;
        for (int k = 0; k < 3; k++) {
            int s2i = 1 + blk * 3 + k;
            // P3 = sc2*spmm_raw(in_x) + cnt*sh2 + bip   (k=0: in_x = bip, no corr)
            const bfl* in_x = (k == 0) ? bip : P4;
            const float* s2 = (k == 0) ? nullptr : slot(s2i - 1);
            dag_spmm<<<spmmGrid, 256, 0, stream>>>(in_x, bip, rowptr, csr_src, P3, N, s2);
            // conv(k): P3 -> P4 (raw; bn2 partials -> part)
            gemm_rw<4, 0, true, false, false, true><<<gemmGrid, 256, 0, stream>>>(
                P3, wt_conv + (size_t)k * 16384, conv_b + k * D128, P4, N, part);
            // finalize bn2 -> slot(s2i) AND build wt2/bias2
            dag_finalize<true><<<1, 256, 0, stream>>>(part,
                                                      bn2_g + k * D128, bn2_b + k * D128, invN,
                                                      slot(s2i), wt_kw + (size_t)k * 16384, wt2, bias2);
            // kw(k): P2 (+)= P4 @ wt2 + bias2; k=2 also writes bn3 partials
            if (k == 0)
                gemm_rw<4, 0, true, false, false, false><<<gemmGrid, 256, 0, stream>>>(
                    P4, wt2, bias2, P2, N, nullptr);
            else if (k == 1)
                gemm_rw<4, 0, true, false, true, false><<<gemmGrid, 256, 0, stream>>>(
                    P4, wt2, bias2, P2, N, nullptr);
            else
                gemm_rw<4, 0, true, false, true, true><<<gemmGrid, 256, 0, stream>>>(
                    P4, wt2, bias2, P2, N, part);
        }
        dag_finalize<false><<<1, 256, 0, stream>>>(part, bn3_g, bn3_b, invN,
                                                   slot(10 + blk), nullptr, nullptr, nullptr);
        // blk<2: only P1 = relu(bn3(P2)) + P0 is consumed (P2 overwritten next
        // block by kw k=0) -> skip dead P2 write.  blk==2: write P2 (pool reads).
        if (blk < 2)
            dag_bn_apply<true, true, false><<<2048, 256, 0, stream>>>(P2, slot(10 + blk),
                                                                      (size_t)N * D128 / 8, P0, P1);
        else
            dag_bn_apply<true, false, true><<<2048, 256, 0, stream>>>(P2, slot(10 + blk),
                                                                      (size_t)N * D128 / 8, nullptr, nullptr);
    }

    // ---- attention pooling (bna partials from tanh-gemm)
    gemm_rw<4, 0, true, true, false, true><<<gemmGrid, 256, 0, stream>>>(
        P2, wt_attn, attn_b1, P3, N, part);
    dag_finalize<false><<<1, 256, 0, stream>>>(part, bna_g, bna_b, invN,
                                               slot(13), nullptr, nullptr, nullptr);
    dag_gemm5<<<(N + 31) / 32, 256, 0, stream>>>(P3, attn_W2, attn_b2, a2, N, slot(13));
    dag_colstat_f32<<<256, 255, 0, stream>>>(a2, N, 5, slot(14));
    dag_alpha<<<(N + 255) / 256, 256, 0, stream>>>(a2, N, slot(14), bnb_g, bnb_b, invN);
    dag_pool<<<G, 128, 0, stream>>>(a2, P2, seg, N, G, (float*)d_out);
}

// Round 19
// 1131.098 us; speedup vs baseline: 1.3893x; 1.0238x over previous
//
#include <hip/hip_runtime.h>
#include <hip/hip_bf16.h>

#define D128 128
#define EPS 1e-5f

typedef unsigned short bfl;
typedef __bf16 bf16x8 __attribute__((ext_vector_type(8)));
typedef float f32x4 __attribute__((ext_vector_type(4)));

__device__ inline float bf2f(unsigned short u) { return __uint_as_float(((unsigned int)u) << 16); }
__device__ inline unsigned short f2bf(float f) {
    unsigned int x = __float_as_uint(f);
    return (unsigned short)((x + 0x7fffu + ((x >> 16) & 1u)) >> 16);  // RNE
}

// ---------------------------------------------------------------- CSR build
__global__ void dag_count_rank(const int* __restrict__ dst, int E,
                               int* __restrict__ deg, int* __restrict__ rank) {
    int i = blockIdx.x * blockDim.x + threadIdx.x;
    int stride = gridDim.x * blockDim.x;
    for (; i < E; i += stride) {
        int r = atomicAdd(&deg[dst[i]], 1);
        rank[i] = r;
    }
}

__global__ void dag_scan1(const int* __restrict__ deg, int N, int* __restrict__ out, int* __restrict__ partials) {
    __shared__ int sdata[256];
    int t = threadIdx.x;
    int base = blockIdx.x * 1024 + t * 4;
    int v[4]; int s = 0;
#pragma unroll
    for (int j = 0; j < 4; j++) { int idx = base + j; v[j] = (idx < N) ? deg[idx] : 0; s += v[j]; }
    sdata[t] = s; __syncthreads();
    for (int off = 1; off < 256; off <<= 1) {
        int x = (t >= off) ? sdata[t - off] : 0;
        __syncthreads();
        sdata[t] += x;
        __syncthreads();
    }
    int run = (t == 0) ? 0 : sdata[t - 1];
#pragma unroll
    for (int j = 0; j < 4; j++) { int idx = base + j; if (idx < N) out[idx] = run; run += v[j]; }
    if (t == 255) partials[blockIdx.x] = sdata[255];
}

__global__ void dag_scan2(int* __restrict__ partials, int P) {
    __shared__ int sdata[256];
    int t = threadIdx.x;
    int v = (t < P) ? partials[t] : 0;
    sdata[t] = v; __syncthreads();
    for (int off = 1; off < 256; off <<= 1) {
        int x = (t >= off) ? sdata[t - off] : 0;
        __syncthreads();
        sdata[t] += x;
        __syncthreads();
    }
    if (t < P) partials[t] = sdata[t] - v;  // exclusive
}

__global__ void dag_scan3(int* __restrict__ rowptr, const int* __restrict__ partials, int N, int E) {
    int i = blockIdx.x * blockDim.x + threadIdx.x;
    int stride = gridDim.x * blockDim.x;
    for (; i < N; i += stride) rowptr[i] += partials[i >> 10];
    if (blockIdx.x == 0 && threadIdx.x == 0) rowptr[N] = E;
}

__global__ void dag_place(const int* __restrict__ src, const int* __restrict__ dst,
                          const int* __restrict__ rank, const int* __restrict__ rowptr,
                          int E, int* __restrict__ csr_src) {
    int i = blockIdx.x * blockDim.x + threadIdx.x;
    int stride = gridDim.x * blockDim.x;
    for (; i < E; i += stride) {
        csr_src[rowptr[dst[i]] + rank[i]] = src[i];
    }
}

// ------------- weight convert: fp32 row-major -> bf16 transposed ----------
__global__ void dag_wconv(const float* __restrict__ node_W, const float* __restrict__ conv_W,
                          const float* __restrict__ k_weight, const float* __restrict__ attn_W1,
                          bfl* __restrict__ wt) {
    int i = blockIdx.x * blockDim.x + threadIdx.x;
    if (i >= 122880) return;
    float v;
    if (i < 8192) {                       // node_W [64,128] -> [128][64]
        int n = i >> 6, k = i & 63;
        v = node_W[k * 128 + n];
    } else if (i < 8192 + 49152) {        // conv_W [3][128][128] -> 3x[128][128]T
        int j = i - 8192; int k = j >> 14; int r = j & 16383;
        int n = r >> 7, kk = r & 127;
        v = conv_W[k * 16384 + kk * 128 + n];
    } else if (i < 8192 + 98304) {        // k_weight [384,128] -> 3x[128][128]T
        int j = i - 8192 - 49152; int k = j >> 14; int r = j & 16383;
        int n = r >> 7, kk = r & 127;
        v = k_weight[(k * 128 + kk) * 128 + n];
    } else {                              // attn_W1 [128,128] -> [128][128]T
        int j = i - 8192 - 98304;
        int n = j >> 7, kk = j & 127;
        v = attn_W1[kk * 128 + n];
    }
    wt[i] = f2bf(v);
}

// ---- finalize: sum 8 partial rows -> sc/sh; re-zero; optional kw fold ----
template<bool KWPREP>
__global__ void dag_finalize(float* __restrict__ part,
                             const float* __restrict__ g, const float* __restrict__ b,
                             float invN, float* __restrict__ slot,
                             const bfl* __restrict__ WtIn, bfl* __restrict__ Wt2,
                             float* __restrict__ bias2) {
    int t = threadIdx.x;  // 256
    float acc = 0.f;
#pragma unroll
    for (int i = 0; i < 8; i++) acc += part[i * 256 + t];
#pragma unroll
    for (int i = 0; i < 8; i++) part[i * 256 + t] = 0.f;   // ready for next use
    __shared__ float sums[256];
    __shared__ float scs[128], shs[128];
    sums[t] = acc;
    __syncthreads();
    if (t < 128) {
        float m = sums[t] * invN;
        float var = sums[128 + t] * invN - m * m;
        float scale = g[t] * rsqrtf(var + EPS);
        float shift = b[t] - m * scale;
        scs[t] = scale; shs[t] = shift;
        slot[t] = scale; slot[128 + t] = shift;
    }
    if constexpr (KWPREP) {
        __syncthreads();
        int row = t >> 1, half = t & 1;
        const bfl* wr = WtIn + row * 128 + half * 64;
        bfl* w2 = Wt2 + row * 128 + half * 64;
        float a = 0.f;
        for (int k = 0; k < 64; k += 8) {
            bf16x8 v = *(const bf16x8*)(wr + k);
            bfl o[8];
#pragma unroll
            for (int j = 0; j < 8; j++) {
                float f = (float)v[j];
                int kk = half * 64 + k + j;
                a += shs[kk] * f;
                o[j] = f2bf(scs[kk] * f);
            }
            *(bf16x8*)(w2 + k) = *(bf16x8*)o;
        }
        a += __shfl_xor(a, 1);
        if (half == 0) bias2[row] = a;
    }
}

// ----------------- register-weight MFMA GEMM, paired tiles ----------------
template<int KSTEPS, int XMODE, bool BIAS, bool TANH, bool ACC, bool STATS>
__global__ __launch_bounds__(256) void gemm_rw(
        const void* __restrict__ Xv, const bfl* __restrict__ Wt,
        const float* __restrict__ bias, bfl* __restrict__ Y,
        int Nrows, float* __restrict__ partOut) {
    const int Kdim = KSTEPS * 32;
    int t = threadIdx.x;
    int lane = t & 63;
    int wave = t >> 6;
    int cg = wave & 1, rg = wave >> 1;
    int l15 = lane & 15, lg = lane >> 4;

    bf16x8 af[4][KSTEPS];
#pragma unroll
    for (int nf = 0; nf < 4; nf++)
#pragma unroll
        for (int ks = 0; ks < KSTEPS; ks++)
            af[nf][ks] = *(const bf16x8*)(Wt + (size_t)(cg * 64 + nf * 16 + l15) * Kdim + ks * 32 + lg * 8);

    float bia[4][4];
    if (BIAS) {
#pragma unroll
        for (int nf = 0; nf < 4; nf++) {
            float4 bb = *(const float4*)(bias + cg * 64 + nf * 16 + lg * 4);
            bia[nf][0] = bb.x; bia[nf][1] = bb.y; bia[nf][2] = bb.z; bia[nf][3] = bb.w;
        }
    }

    float s_c[4][4], q_c[4][4];
    if constexpr (STATS) {
#pragma unroll
        for (int nf = 0; nf < 4; nf++)
#pragma unroll
            for (int j = 0; j < 4; j++) { s_c[nf][j] = 0.f; q_c[nf][j] = 0.f; }
    }

    const int RT = (Nrows + 15) >> 4;
    const int step = gridDim.x * 2;

    auto load_bf = [&](int rt, bf16x8* bfo) {
        int r = rt * 16 + l15;
        bool valid = (rt < RT) && (r < Nrows);
#pragma unroll
        for (int ks = 0; ks < KSTEPS; ks++) {
            if (valid) {
                if (XMODE == 0) {
                    bfo[ks] = *(const bf16x8*)((const bfl*)Xv + (size_t)r * Kdim + ks * 32 + lg * 8);
                } else {
                    const float* xp = (const float*)Xv + (size_t)r * Kdim + ks * 32 + lg * 8;
                    float4 a4 = *(const float4*)xp;
                    float4 b4 = *(const float4*)(xp + 4);
                    bf16x8 bb;
                    bb[0] = (__bf16)a4.x; bb[1] = (__bf16)a4.y; bb[2] = (__bf16)a4.z; bb[3] = (__bf16)a4.w;
                    bb[4] = (__bf16)b4.x; bb[5] = (__bf16)b4.y; bb[6] = (__bf16)b4.z; bb[7] = (__bf16)b4.w;
                    bfo[ks] = bb;
                }
            } else {
                bf16x8 bb;
#pragma unroll
                for (int j = 0; j < 8; j++) bb[j] = (__bf16)0.f;
                bfo[ks] = bb;
            }
        }
    };

    auto compute_store = [&](int rt, const bf16x8* bfc) {
        int r = rt * 16 + l15;
        bool valid = (rt < RT) && (r < Nrows);
        f32x4 acc[4];
#pragma unroll
        for (int nf = 0; nf < 4; nf++) acc[nf] = (f32x4)0.f;
#pragma unroll
        for (int ks = 0; ks < KSTEPS; ks++)
#pragma unroll
            for (int nf = 0; nf < 4; nf++)
                acc[nf] = __builtin_amdgcn_mfma_f32_16x16x32_bf16(af[nf][ks], bfc[ks], acc[nf], 0, 0, 0);
#pragma unroll
        for (int nf = 0; nf < 4; nf++) {
            int c0 = cg * 64 + nf * 16 + lg * 4;
            f32x4 v = acc[nf];
            if (BIAS) {
#pragma unroll
                for (int j = 0; j < 4; j++) v[j] += bia[nf][j];
            }
            if (TANH) {
#pragma unroll
                for (int j = 0; j < 4; j++) v[j] = tanhf(v[j]);
            }
            if (valid) {
                bfl* yp = Y + (size_t)r * D128 + c0;
                if (ACC) {
                    ushort4 old = *(const ushort4*)yp;
                    v[0] += bf2f(old.x); v[1] += bf2f(old.y); v[2] += bf2f(old.z); v[3] += bf2f(old.w);
                }
                ushort4 o;
                o.x = f2bf(v[0]); o.y = f2bf(v[1]); o.z = f2bf(v[2]); o.w = f2bf(v[3]);
                *(ushort4*)yp = o;
            }
            if constexpr (STATS) {
#pragma unroll
                for (int j = 0; j < 4; j++) {
                    float f = valid ? v[j] : 0.f;
                    s_c[nf][j] += f;
                    q_c[nf][j] += f * f;
                }
            }
        }
    };

    for (int rt = blockIdx.x * 2 + rg; rt < RT; rt += 2 * step) {
        bf16x8 bfA[KSTEPS], bfB[KSTEPS];
        load_bf(rt, bfA);
        load_bf(rt + step, bfB);
        compute_store(rt, bfA);
        compute_store(rt + step, bfB);
    }

    if constexpr (STATS) {
#pragma unroll
        for (int nf = 0; nf < 4; nf++)
#pragma unroll
            for (int j = 0; j < 4; j++) {
                float s = s_c[nf][j], q = q_c[nf][j];
                s += __shfl_xor(s, 1); s += __shfl_xor(s, 2); s += __shfl_xor(s, 4); s += __shfl_xor(s, 8);
                q += __shfl_xor(q, 1); q += __shfl_xor(q, 2); q += __shfl_xor(q, 4); q += __shfl_xor(q, 8);
                s_c[nf][j] = s; q_c[nf][j] = q;
            }
        __shared__ float red[2][2][64];   // [cg][stat][col]
        ((float*)red)[t] = 0.f;
        __syncthreads();
        if (l15 == 0) {
#pragma unroll
            for (int nf = 0; nf < 4; nf++)
#pragma unroll
                for (int j = 0; j < 4; j++) {
                    int c = nf * 16 + lg * 4 + j;
                    atomicAdd(&red[cg][0][c], s_c[nf][j]);   // LDS atomics (block-local)
                    atomicAdd(&red[cg][1][c], q_c[nf][j]);
                }
        }
        __syncthreads();
        int cgi = t >> 7, stat = (t >> 6) & 1, c = t & 63;
        atomicAdd(&partOut[(size_t)(blockIdx.x & 7) * 256 + stat * 128 + cgi * 64 + c],
                  red[cgi][stat][c]);
    }
}

// --------- spmm, 4 nodes per wave: 16 lanes x 16B per node ---------------
__global__ __launch_bounds__(256) void dag_spmm(
        const bfl* __restrict__ x, const bfl* __restrict__ bi,
        const int* __restrict__ rowptr, const int* __restrict__ csr_src,
        bfl* __restrict__ out, int N, const float* __restrict__ scsh) {
    int t = threadIdx.x;
    int lane = t & 63;
    int wave = t >> 6;
    int l16 = lane & 15;
    int sub = lane >> 4;                  // node within wave (0..3)
    int c0 = l16 * 8;                     // bf16 column (8 cols = 16B per lane)
    int n = blockIdx.x * 16 + wave * 4 + sub;
    bool valid = n < N;

    float sc[8], sh[8];
    if (scsh) {
        float4 a = *(const float4*)(scsh + c0);
        float4 b = *(const float4*)(scsh + c0 + 4);
        float4 p = *(const float4*)(scsh + 128 + c0);
        float4 q = *(const float4*)(scsh + 128 + c0 + 4);
        sc[0] = a.x; sc[1] = a.y; sc[2] = a.z; sc[3] = a.w;
        sc[4] = b.x; sc[5] = b.y; sc[6] = b.z; sc[7] = b.w;
        sh[0] = p.x; sh[1] = p.y; sh[2] = p.z; sh[3] = p.w;
        sh[4] = q.x; sh[5] = q.y; sh[6] = q.z; sh[7] = q.w;
    } else {
#pragma unroll
        for (int j = 0; j < 8; j++) { sc[j] = 1.f; sh[j] = 0.f; }
    }

    int p0 = valid ? rowptr[n] : 0;
    int p1 = valid ? rowptr[n + 1] : 0;
    int deg = p1 - p0;
    int md = deg;
    md = max(md, __shfl_xor(md, 16));
    md = max(md, __shfl_xor(md, 32));

    uint4 ub = make_uint4(0, 0, 0, 0);
    if (valid) ub = *(const uint4*)(bi + (size_t)n * D128 + c0);

    const bfl* xb = x + c0;
    float acc[8];
#pragma unroll
    for (int j = 0; j < 8; j++) acc[j] = 0.f;

    for (int j = 0; j < md; j += 4) {
        uint4 u[4];
#pragma unroll
        for (int r = 0; r < 4; r++) {
            u[r] = make_uint4(0, 0, 0, 0);
            if (j + r < deg) {
                int s = csr_src[p0 + j + r];
                u[r] = *(const uint4*)(xb + (size_t)s * D128);
            }
        }
#pragma unroll
        for (int r = 0; r < 4; r++) {
            acc[0] += __uint_as_float(u[r].x << 16);
            acc[1] += __uint_as_float(u[r].x & 0xffff0000u);
            acc[2] += __uint_as_float(u[r].y << 16);
            acc[3] += __uint_as_float(u[r].y & 0xffff0000u);
            acc[4] += __uint_as_float(u[r].z << 16);
            acc[5] += __uint_as_float(u[r].z & 0xffff0000u);
            acc[6] += __uint_as_float(u[r].w << 16);
            acc[7] += __uint_as_float(u[r].w & 0xffff0000u);
        }
    }

    if (valid) {
        float cnt = (float)deg;
        float bv[8];
        bv[0] = __uint_as_float(ub.x << 16); bv[1] = __uint_as_float(ub.x & 0xffff0000u);
        bv[2] = __uint_as_float(ub.y << 16); bv[3] = __uint_as_float(ub.y & 0xffff0000u);
        bv[4] = __uint_as_float(ub.z << 16); bv[5] = __uint_as_float(ub.z & 0xffff0000u);
        bv[6] = __uint_as_float(ub.w << 16); bv[7] = __uint_as_float(ub.w & 0xffff0000u);
        float v[8];
#pragma unroll
        for (int j = 0; j < 8; j++) v[j] = sc[j] * acc[j] + cnt * sh[j] + bv[j];
        uint4 o;
        o.x = (unsigned int)f2bf(v[0]) | ((unsigned int)f2bf(v[1]) << 16);
        o.y = (unsigned int)f2bf(v[2]) | ((unsigned int)f2bf(v[3]) << 16);
        o.z = (unsigned int)f2bf(v[4]) | ((unsigned int)f2bf(v[5]) << 16);
        o.w = (unsigned int)f2bf(v[6]) | ((unsigned int)f2bf(v[7]) << 16);
        *(uint4*)(out + (size_t)n * D128 + c0) = o;
    }
}

// ----------------- column stats fp32, small C (a2 [N,5]) ------------------
__global__ void dag_colstat_f32(const float* __restrict__ Y, int Nrows, int C, float* __restrict__ sums) {
    __shared__ float ls[8], lss[8];
    int t = threadIdx.x;
    int nlanes = blockDim.x / C;
    int col = t % C, lane = t / C;
    float s = 0.f, ss = 0.f;
    if (lane < nlanes) {
        for (int r = blockIdx.x * nlanes + lane; r < Nrows; r += gridDim.x * nlanes) {
            float v = Y[(size_t)r * C + col];
            s += v; ss += v * v;
        }
    }
    if (t < C) { ls[t] = 0.f; lss[t] = 0.f; }
    __syncthreads();
    if (lane < nlanes) { atomicAdd(&ls[col], s); atomicAdd(&lss[col], ss); }
    __syncthreads();
    if (t < C) { atomicAdd(&sums[t], ls[t]); atomicAdd(&sums[C + t], lss[t]); }
}

// --------- BN apply using finalized sc/sh; WRITEY=false skips Y store -----
template<bool RELU, bool ADDOUT, bool WRITEY>
__global__ void dag_bn_apply(bfl* __restrict__ Y, const float* __restrict__ scsh,
                             size_t n8,
                             const bfl* __restrict__ addin, bfl* __restrict__ out2) {
    __shared__ float sc[128], sh[128];
    int t = threadIdx.x;
    if (t < 128) {
        sc[t] = scsh[t];
        sh[t] = scsh[128 + t];
    }
    __syncthreads();
    for (size_t i = (size_t)blockIdx.x * blockDim.x + t; i < n8; i += (size_t)gridDim.x * blockDim.x) {
        int c0 = (int)((i * 8) & 127);
        bf16x8 v = *(bf16x8*)(Y + i * 8);
        bfl o[8], o2[8];
#pragma unroll
        for (int j = 0; j < 8; j++) {
            float f = (float)v[j] * sc[c0 + j] + sh[c0 + j];
            if (RELU) f = fmaxf(f, 0.f);
            o[j] = f2bf(f);
            if (ADDOUT) o2[j] = f2bf(f + bf2f(addin[i * 8 + j]));
        }
        if (WRITEY) *(bf16x8*)(Y + i * 8) = *(bf16x8*)o;
        if (ADDOUT) *(bf16x8*)(out2 + i * 8) = *(bf16x8*)o2;
    }
}

// --------------- small GEMM: Y[N,5] = (sc/sh-corrected X) @ W + b ---------
__global__ void dag_gemm5(const bfl* __restrict__ X, const float* __restrict__ W,
                          const float* __restrict__ bias, float* __restrict__ Y, int Nrows,
                          const float* __restrict__ scsh) {
    __shared__ float Xs[32][132];
    __shared__ float Ws[640];
    __shared__ float sc[128], sh[128];
    int t = threadIdx.x;
    if (t < 128) {
        sc[t] = scsh[t];
        sh[t] = scsh[128 + t];
    }
    for (int i = t; i < 640; i += 256) Ws[i] = W[i];
    __syncthreads();
    int row0 = blockIdx.x * 32;
#pragma unroll
    for (int i = 0; i < 2; i++) {
        int off = (i * 256 + t) * 8;
        int r = off >> 7, c = off & 127;
        int gr = row0 + r;
        if (gr < Nrows) {
            bf16x8 v = *(const bf16x8*)(X + (size_t)gr * D128 + c);
#pragma unroll
            for (int j = 0; j < 8; j++) Xs[r][c + j] = (float)v[j] * sc[c + j] + sh[c + j];
        } else {
#pragma unroll
            for (int j = 0; j < 8; j++) Xs[r][c + j] = 0.f;
        }
    }
    __syncthreads();
    if (t < 160) {
        int r = t / 5, h = t % 5;
        int gr = row0 + r;
        if (gr < Nrows) {
            float s = bias[h];
            for (int k = 0; k < 128; k++) s = fmaf(Xs[r][k], Ws[k * 5 + h], s);
            Y[(size_t)gr * 5 + h] = s;
        }
    }
}

// --------------- alpha: in-place bnb + softmax over 5 heads ---------------
__global__ void dag_alpha(float* __restrict__ a2, int N,
                          const float* __restrict__ sums, const float* __restrict__ g,
                          const float* __restrict__ b, float invN) {
    float scb[5], shb[5];
#pragma unroll
    for (int h = 0; h < 5; h++) {
        float s = sums[h], ss = sums[5 + h];
        float m = s * invN;
        float var = ss * invN - m * m;
        float scale = g[h] * rsqrtf(var + EPS);
        scb[h] = scale; shb[h] = b[h] - m * scale;
    }
    int n = blockIdx.x * blockDim.x + threadIdx.x;
    if (n >= N) return;
    float av[5];
    float mx = -1e30f;
#pragma unroll
    for (int h = 0; h < 5; h++) {
        av[h] = a2[(size_t)n * 5 + h] * scb[h] + shb[h];
        mx = fmaxf(mx, av[h]);
    }
    float s = 0.f;
#pragma unroll
    for (int h = 0; h < 5; h++) { av[h] = expf(av[h] - mx); s += av[h]; }
    float inv = 1.f / s;
#pragma unroll
    for (int h = 0; h < 5; h++) a2[(size_t)n * 5 + h] = av[h] * inv;
}

// --------------- attention pooling, 256 threads, 4-deep pipeline ----------
// Two 128-thread halves process interleaved nodes (stride 2), each half
// unrolled 2-deep (stride 4) -> 4 independent emb loads in flight; LDS
// combine at the end.
__global__ __launch_bounds__(256) void dag_pool(
        const float* __restrict__ alpha, const bfl* __restrict__ emb,
        const int* __restrict__ seg, int N, int G, float* __restrict__ out) {
    int gg = blockIdx.x;
    int t = threadIdx.x;
    int d = t & 127;
    int half = t >> 7;   // 0 or 1
    int lo = 0, hi = N;
    while (lo < hi) { int m = (lo + hi) >> 1; if (seg[m] < gg) lo = m + 1; else hi = m; }
    int start = lo;
    lo = start; hi = N;
    while (lo < hi) { int m = (lo + hi) >> 1; if (seg[m] < gg + 1) lo = m + 1; else hi = m; }
    int end = lo;

    float acc0[5] = {0.f, 0.f, 0.f, 0.f, 0.f};
    float acc1[5] = {0.f, 0.f, 0.f, 0.f, 0.f};
    int n = start + half;
    for (; n + 2 < end; n += 4) {
        float e0 = bf2f(emb[(size_t)n * D128 + d]);
        float e1 = bf2f(emb[(size_t)(n + 2) * D128 + d]);
#pragma unroll
        for (int h = 0; h < 5; h++) {
            acc0[h] = fmaf(alpha[(size_t)n * 5 + h], e0, acc0[h]);
            acc1[h] = fmaf(alpha[(size_t)(n + 2) * 5 + h], e1, acc1[h]);
        }
    }
    for (; n < end; n += 2) {
        float e0 = bf2f(emb[(size_t)n * D128 + d]);
#pragma unroll
        for (int h = 0; h < 5; h++)
            acc0[h] = fmaf(alpha[(size_t)n * 5 + h], e0, acc0[h]);
    }
#pragma unroll
    for (int h = 0; h < 5; h++) acc0[h] += acc1[h];

    __shared__ float red[5][128];
    if (half == 1) {
#pragma unroll
        for (int h = 0; h < 5; h++) red[h][d] = acc0[h];
    }
    __syncthreads();
    if (half == 0) {
#pragma unroll
        for (int h = 0; h < 5; h++)
            out[(size_t)gg * 640 + h * D128 + d] = fmaxf(acc0[h] + red[h][d], 0.f);
    }
}

// --------------- L1 regularizer (multi-block) -----------------------------
__global__ void dag_reg(const float* w0, int n0, const float* w1, int n1, const float* w2, int n2,
                        const float* w3, int n3, const float* w4, int n4, float* out, float invG) {
    __shared__ float sd[256];
    int t = threadIdx.x;
    int gt = blockIdx.x * blockDim.x + t;
    int stride = gridDim.x * blockDim.x;
    float s = 0.f;
    const float* ws[5] = {w0, w1, w2, w3, w4};
    int ns[5] = {n0, n1, n2, n3, n4};
    for (int a = 0; a < 5; a++) {
        const float* w = ws[a]; int n = ns[a];
        for (int i = gt; i < n; i += stride) s += fabsf(w[i]);
    }
    sd[t] = s; __syncthreads();
    for (int off = 128; off > 0; off >>= 1) { if (t < off) sd[t] += sd[t + off]; __syncthreads(); }
    if (t == 0) atomicAdd(out, sd[0] * invG);
}

// ================================================================ host side
extern "C" void kernel_launch(void* const* d_in, const int* in_sizes, int n_in,
                              void* d_out, int out_size, void* d_ws, size_t ws_size,
                              hipStream_t stream) {
    const float* node_feat = (const float*)d_in[0];
    const int*   src       = (const int*)d_in[1];
    const int*   dst       = (const int*)d_in[2];
    const int*   seg       = (const int*)d_in[3];
    const float* node_W    = (const float*)d_in[4];
    const float* node_b    = (const float*)d_in[5];
    const float* bn1_g     = (const float*)d_in[6];
    const float* bn1_b     = (const float*)d_in[7];
    const float* conv_W    = (const float*)d_in[8];
    const float* conv_b    = (const float*)d_in[9];
    const float* bn2_g     = (const float*)d_in[10];
    const float* bn2_b     = (const float*)d_in[11];
    const float* k_weight  = (const float*)d_in[12];
    const float* bn3_g     = (const float*)d_in[13];
    const float* bn3_b     = (const float*)d_in[14];
    const float* attn_W1   = (const float*)d_in[15];
    const float* attn_b1   = (const float*)d_in[16];
    const float* bna_g     = (const float*)d_in[17];
    const float* bna_b     = (const float*)d_in[18];
    const float* attn_W2   = (const float*)d_in[19];
    const float* attn_b2   = (const float*)d_in[20];
    const float* bnb_g     = (const float*)d_in[21];
    const float* bnb_b     = (const float*)d_in[22];

    const int N = in_sizes[3];
    const int E = in_sizes[1];
    const int G = (out_size - 1) / 640;
    const int FIN = in_sizes[0] / N;
    const float invN = 1.f / (float)N;

    // ---- workspace layout (all bf16 activations)
    auto align256 = [](size_t x) { return (x + 255) & ~(size_t)255; };
    size_t NB = (size_t)N * D128 * sizeof(bfl);   // 25.6 MB
    char* w = (char*)d_ws;
    bfl* P0 = (bfl*)(w + 0 * NB);   // inp (bn1 out)
    bfl* P1 = (bfl*)(w + 1 * NB);   // bi (block_input)
    bfl* P2 = (bfl*)(w + 2 * NB);   // cur / kgemm accumulator
    bfl* P3 = (bfl*)(w + 3 * NB);   // pooled / attn A
    bfl* P4 = (bfl*)(w + 4 * NB);   // O_k raw
    char* tail = w + 5 * NB;
    size_t off = 0;
    int gemmGrid = (N + 127) / 128;   // 782
    float* stats = (float*)(tail + off); off = align256(off + 15 * 256 * sizeof(float));
    float* part  = (float*)(tail + off); off = align256(off + 8 * 256 * sizeof(float));
    bfl*   wt    = (bfl*)(tail + off);   off = align256(off + 122880 * sizeof(bfl));
    bfl*   wt2   = (bfl*)(tail + off);   off = align256(off + 16384 * sizeof(bfl));
    float* bias2 = (float*)(tail + off); off = align256(off + 128 * sizeof(float));
    float* a2    = (float*)(tail + off); off = align256(off + (size_t)N * 5 * sizeof(float));
    int* deg     = (int*)(tail + off);   off = align256(off + (size_t)N * 4);
    int* rowptr  = (int*)(tail + off);   off = align256(off + (size_t)(N + 1) * 4);
    int* rank    = (int*)(tail + off);   off = align256(off + (size_t)E * 4);
    int* csr_src = (int*)(tail + off);   off = align256(off + (size_t)E * 4);
    int* partials= (int*)(tail + off);   off = align256(off + 512);

    bfl* wt_node = wt;
    bfl* wt_conv = wt + 8192;
    bfl* wt_kw   = wt + 8192 + 49152;
    bfl* wt_attn = wt + 8192 + 98304;
    auto slot = [&](int s) { return stats + (size_t)s * 256; };
    // slots 0..13 hold finalized {sc[128], sh[128]}; slot 14 = raw bnb sums

    int spmmGrid = (N + 15) / 16;   // 4 nodes per wave, 4 waves per block

    // ---- zero part accumulator (8 rows), slot14 sums, reg output slot
    hipMemsetAsync(part, 0, 8 * 256 * sizeof(float), stream);
    hipMemsetAsync(slot(14), 0, 256 * sizeof(float), stream);
    hipMemsetAsync((float*)d_out + (size_t)G * 640, 0, 4, stream);

    // ---- CSR build (by dst): one atomic pass + scan + non-atomic place
    hipMemsetAsync(deg, 0, (size_t)N * 4, stream);
    dag_count_rank<<<1024, 256, 0, stream>>>(dst, E, deg, rank);
    int P = (N + 1023) / 1024;
    dag_scan1<<<P, 256, 0, stream>>>(deg, N, rowptr, partials);
    dag_scan2<<<1, 256, 0, stream>>>(partials, P);
    dag_scan3<<<256, 256, 0, stream>>>(rowptr, partials, N, E);
    dag_place<<<1024, 256, 0, stream>>>(src, dst, rank, rowptr, E, csr_src);

    // ---- weights -> bf16 transposed
    dag_wconv<<<480, 256, 0, stream>>>(node_W, conv_W, k_weight, attn_W1, wt);

    // ---- L1 reg (independent)
    dag_reg<<<64, 256, 0, stream>>>(node_W, FIN * D128, conv_W, 3 * D128 * D128,
                                    k_weight, 3 * D128 * D128, attn_W1, D128 * D128,
                                    attn_W2, D128 * 5, (float*)d_out + (size_t)G * 640, 1.0f / G);

    // ---- node embedding: P0 = relu(bn1(node_feat @ node_W + node_b))
    gemm_rw<2, 1, true, false, false, true><<<gemmGrid, 256, 0, stream>>>(
        node_feat, wt_node, node_b, P0, N, part);
    dag_finalize<false><<<1, 256, 0, stream>>>(part, bn1_g, bn1_b, invN,
                                               slot(0), nullptr, nullptr, nullptr);
    dag_bn_apply<true, false, true><<<2048, 256, 0, stream>>>(P0, slot(0), (size_t)N * D128 / 8,
                                                              nullptr, nullptr);

    // ---- 3 blocks
    for (int blk = 0; blk < 3; blk++) {
        const bfl* bip = (blk == 0) ? P0 : P1;
        for (int k = 0; k < 3; k++) {
            int s2i = 1 + blk * 3 + k;
            // P3 = sc2*spmm_raw(in_x) + cnt*sh2 + bip   (k=0: in_x = bip, no corr)
            const bfl* in_x = (k == 0) ? bip : P4;
            const float* s2 = (k == 0) ? nullptr : slot(s2i - 1);
            dag_spmm<<<spmmGrid, 256, 0, stream>>>(in_x, bip, rowptr, csr_src, P3, N, s2);
            // conv(k): P3 -> P4 (raw; bn2 partials -> part)
            gemm_rw<4, 0, true, false, false, true><<<gemmGrid, 256, 0, stream>>>(
                P3, wt_conv + (size_t)k * 16384, conv_b + k * D128, P4, N, part);
            // finalize bn2 -> slot(s2i) AND build wt2/bias2
            dag_finalize<true><<<1, 256, 0, stream>>>(part,
                                                      bn2_g + k * D128, bn2_b + k * D128, invN,
                                                      slot(s2i), wt_kw + (size_t)k * 16384, wt2, bias2);
            // kw(k): P2 (+)= P4 @ wt2 + bias2; k=2 also writes bn3 partials
            if (k == 0)
                gemm_rw<4, 0, true, false, false, false><<<gemmGrid, 256, 0, stream>>>(
                    P4, wt2, bias2, P2, N, nullptr);
            else if (k == 1)
                gemm_rw<4, 0, true, false, true, false><<<gemmGrid, 256, 0, stream>>>(
                    P4, wt2, bias2, P2, N, nullptr);
            else
                gemm_rw<4, 0, true, false, true, true><<<gemmGrid, 256, 0, stream>>>(
                    P4, wt2, bias2, P2, N, part);
        }
        dag_finalize<false><<<1, 256, 0, stream>>>(part, bn3_g, bn3_b, invN,
                                                   slot(10 + blk), nullptr, nullptr, nullptr);
        // blk<2: only P1 = relu(bn3(P2)) + P0 is consumed -> skip dead P2 write.
        if (blk < 2)
            dag_bn_apply<true, true, false><<<2048, 256, 0, stream>>>(P2, slot(10 + blk),
                                                                      (size_t)N * D128 / 8, P0, P1);
        else
            dag_bn_apply<true, false, true><<<2048, 256, 0, stream>>>(P2, slot(10 + blk),
                                                                      (size_t)N * D128 / 8, nullptr, nullptr);
    }

    // ---- attention pooling (bna partials from tanh-gemm)
    gemm_rw<4, 0, true, true, false, true><<<gemmGrid, 256, 0, stream>>>(
        P2, wt_attn, attn_b1, P3, N, part);
    dag_finalize<false><<<1, 256, 0, stream>>>(part, bna_g, bna_b, invN,
                                               slot(13), nullptr, nullptr, nullptr);
    dag_gemm5<<<(N + 31) / 32, 256, 0, stream>>>(P3, attn_W2, attn_b2, a2, N, slot(13));
    dag_colstat_f32<<<256, 255, 0, stream>>>(a2, N, 5, slot(14));
    dag_alpha<<<(N + 255) / 256, 256, 0, stream>>>(a2, N, slot(14), bnb_g, bnb_b, invN);
    dag_pool<<<G, 256, 0, stream>>>(a2, P2, seg, N, G, (float*)d_out);
}